// Round 15
// baseline (244.148 us; speedup 1.0000x reference)
//
#include <hip/hip_runtime.h>
#include <hip/hip_bf16.h>

#define Bc 8
#define Nn 9216
#define Dd 256
#define Oo 512
#define EPSc 1e-5f

// workspace float offsets
#define OFF_MU1    0          // 73728
#define OFF_RSTD1  73728
#define OFF_MU2    147456
#define OFF_RSTD2  221184
#define OFF_ROWINV 294912
#define OFF_COLSUM 368640     // 2048
#define OFF_M      370688     // 524288
#define OFF_W2T    894976     // W2 bf16 frag-linear: 1,048,576 ushorts
#define OFF_CTXP   1419264    // nks * 524288 floats of ctx partials
#define OFF_PNB    14002176   // LN(x1) panel bf16 [b][144][16384]: 18,874,368 ushorts
#define OFF_PNA    23439360   // exp(LN(x2)) panel bf16, same shape
#define WS_FAST_END 32876544  // floats needed for fast path

typedef __attribute__((ext_vector_type(4))) float f32x4;
typedef __attribute__((ext_vector_type(8))) short short8;
typedef __attribute__((ext_vector_type(8))) unsigned short ushort8;

static __device__ __forceinline__ unsigned short f2bf(float f) {
    __hip_bfloat16 h = __float2bfloat16(f);
    union { __hip_bfloat16 hh; unsigned short uu; } cv; cv.hh = h;
    return cv.uu;
}

// granule swizzle for channel-major bf16 tiles [ch][64n]
#define SWZ(ch) (((((ch) >> 2) & 7)) ^ ((((ch) & 3)) << 1))

__global__ __launch_bounds__(256) void mg_k0_zero(float* __restrict__ p, int n4) {
    int i = blockIdx.x * 256 + threadIdx.x;
    if (i < n4) ((float4*)p)[i] = make_float4(0.f, 0.f, 0.f, 0.f);
}

// K1 v4 (256-thr pipelined + panel accumulation): per 64-row tile, 16 iterations
// (one row per wave per iter, loads pipeline across iters). LN stats, rowinv,
// colsum; panel images PBi=LN(x1), PAi=exp(LN(x2)) accumulated in LDS via scalar
// bf16 stores, dumped linearly at the end (K3-fast's exact LDS image).
__global__ __launch_bounds__(256) void mg_k1_stats(const float* __restrict__ x1, const float* __restrict__ x2,
                                                   const float* __restrict__ g1, const float* __restrict__ b1,
                                                   float* __restrict__ ws, int wp)
{
    __shared__ ushort PAi[16384];
    __shared__ ushort PBi[16384];
    __shared__ float csL[4][256];
    float* mu1    = ws + OFF_MU1;
    float* rstd1  = ws + OFF_RSTD1;
    float* mu2    = ws + OFF_MU2;
    float* rstd2  = ws + OFF_RSTD2;
    float* rowinv = ws + OFF_ROWINV;
    float* colsum = ws + OFF_COLSUM;

    int t = threadIdx.x, lane = t & 63, w = t >> 6;
    int b = blockIdx.x / 144, rb = blockIdx.x % 144;
    int nbase = rb * 64;

    float4 g1v = ((const float4*)g1)[lane];
    float4 b1v = ((const float4*)b1)[lane];
    float cs0 = 0.f, cs1 = 0.f, cs2 = 0.f, cs3 = 0.f;

    for (int i = 0; i < 16; ++i) {
        int l = i * 4 + w;                 // local row 0..63
        int n = nbase + l;
        int ni = b * Nn + n;
        int base = ni * 64 + lane;
        float4 xa = ((const float4*)x1)[base];
        float4 xb = ((const float4*)x2)[base];
        float s1 = xa.x + xa.y + xa.z + xa.w;
        float q1 = xa.x*xa.x + xa.y*xa.y + xa.z*xa.z + xa.w*xa.w;
        float s2 = xb.x + xb.y + xb.z + xb.w;
        float q2 = xb.x*xb.x + xb.y*xb.y + xb.z*xb.z + xb.w*xb.w;
        #pragma unroll
        for (int m = 1; m < 64; m <<= 1) {
            s1 += __shfl_xor(s1, m); q1 += __shfl_xor(q1, m);
            s2 += __shfl_xor(s2, m); q2 += __shfl_xor(q2, m);
        }
        float m1 = s1 * (1.f / Dd), m2 = s2 * (1.f / Dd);
        float r1 = rsqrtf(q1 * (1.f / Dd) - m1 * m1 + EPSc);
        float r2 = rsqrtf(q2 * (1.f / Dd) - m2 * m2 + EPSc);
        if (lane == 0) { mu1[ni] = m1; rstd1[ni] = r1; mu2[ni] = m2; rstd2[ni] = r2; }
        // LN(x2) values are bounded -> exp without max-subtraction is safe in f32
        float e0 = __expf((xb.x - m2) * r2 * g1v.x + b1v.x);
        float e1 = __expf((xb.y - m2) * r2 * g1v.y + b1v.y);
        float e2 = __expf((xb.z - m2) * r2 * g1v.z + b1v.z);
        float e3 = __expf((xb.w - m2) * r2 * g1v.w + b1v.w);
        float rs = e0 + e1 + e2 + e3;
        #pragma unroll
        for (int m = 1; m < 64; m <<= 1) rs += __shfl_xor(rs, m);
        if (lane == 0) rowinv[ni] = 1.f / rs;
        cs0 += e0; cs1 += e1; cs2 += e2; cs3 += e3;

        if (wp) {
            int oo = l >> 3, r8 = l & 7;
            float ln1[4] = {(xa.x - m1) * r1 * g1v.x + b1v.x,
                            (xa.y - m1) * r1 * g1v.y + b1v.y,
                            (xa.z - m1) * r1 * g1v.z + b1v.z,
                            (xa.w - m1) * r1 * g1v.w + b1v.w};
            float ev[4] = {e0, e1, e2, e3};
            #pragma unroll
            for (int ii = 0; ii < 4; ++ii) {
                int ch = lane * 4 + ii;
                int idx = ch * 64 + (((oo + SWZ(ch)) & 7) << 3) + r8;
                PBi[idx] = f2bf(ln1[ii]);
                PAi[idx] = f2bf(ev[ii]);
            }
        }
    }
    csL[w][lane * 4 + 0] = cs0;
    csL[w][lane * 4 + 1] = cs1;
    csL[w][lane * 4 + 2] = cs2;
    csL[w][lane * 4 + 3] = cs3;
    __syncthreads();
    if (wp) {
        ushort* pnB = (ushort*)(ws + OFF_PNB) + ((size_t)b * 144 + rb) * 16384;
        ushort* pnA = (ushort*)(ws + OFF_PNA) + ((size_t)b * 144 + rb) * 16384;
        #pragma unroll
        for (int k = 0; k < 8; ++k) {
            *(ushort8*)&pnB[k * 2048 + t * 8] = *(const ushort8*)&PBi[k * 2048 + t * 8];
            *(ushort8*)&pnA[k * 2048 + t * 8] = *(const ushort8*)&PAi[k * 2048 + t * 8];
        }
    }
    float tot = csL[0][t] + csL[1][t] + csL[2][t] + csL[3][t];
    atomicAdd(&colsum[b * Dd + t], tot);
}

// K3 fast (pure async GEMM from panels): nks=24 fixed, 6 tiles/block.
__global__ __launch_bounds__(512, 2) void mg_k3_ctx_f(float* __restrict__ ws)
{
    __shared__ ushort PA[16384];
    __shared__ ushort PB[16384];
    const ushort* pnA = (const ushort*)(ws + OFF_PNA);
    const ushort* pnB = (const ushort*)(ws + OFF_PNB);
    float* ctxp = ws + OFF_CTXP;

    int t = threadIdx.x;
    int ks_i = blockIdx.x % 24;
    int b = blockIdx.x / 24;
    int lane = t & 63, wave = t >> 6;
    int wd = wave & 3, we = wave >> 2;
    int l15 = lane & 15, kgrp = lane >> 4;

    f32x4 acc[4][8];
    #pragma unroll
    for (int dt = 0; dt < 4; ++dt)
        #pragma unroll
        for (int et = 0; et < 8; ++et) acc[dt][et] = (f32x4){0.f, 0.f, 0.f, 0.f};

    for (int j = 0; j < 6; ++j) {
        int tile = ks_i * 6 + j;
        size_t tb = ((size_t)b * 144 + tile) * 16384;
        __syncthreads();   // prior MFMA reads done before overwrite
        #pragma unroll
        for (int k = 0; k < 4; ++k) {
            __builtin_amdgcn_global_load_lds(
                (const __attribute__((address_space(1))) unsigned int*)(pnA + tb + wave * 2048 + k * 512 + lane * 8),
                (__attribute__((address_space(3))) unsigned int*)(PA + wave * 2048 + k * 512),
                16, 0, 0);
            __builtin_amdgcn_global_load_lds(
                (const __attribute__((address_space(1))) unsigned int*)(pnB + tb + wave * 2048 + k * 512 + lane * 8),
                (__attribute__((address_space(3))) unsigned int*)(PB + wave * 2048 + k * 512),
                16, 0, 0);
        }
        __syncthreads();   // drain staging

        #pragma unroll
        for (int kk = 0; kk < 2; ++kk) {
            short8 af[4], bf[8];
            #pragma unroll
            for (int dt = 0; dt < 4; ++dt) {
                int ch = wd * 64 + dt * 16 + l15;
                af[dt] = *(const short8*)&PA[ch * 64 + (((kk << 2) + kgrp + SWZ(ch)) & 7) * 8];
            }
            #pragma unroll
            for (int et = 0; et < 8; ++et) {
                int ch = we * 128 + et * 16 + l15;
                bf[et] = *(const short8*)&PB[ch * 64 + (((kk << 2) + kgrp + SWZ(ch)) & 7) * 8];
            }
            #pragma unroll
            for (int dt = 0; dt < 4; ++dt)
                #pragma unroll
                for (int et = 0; et < 8; ++et)
                    acc[dt][et] = __builtin_amdgcn_mfma_f32_16x16x32_bf16(af[dt], bf[et], acc[dt][et], 0, 0, 0);
        }
    }

    size_t obase = ((size_t)ks_i * Bc + b) * (Dd * Dd);
    #pragma unroll
    for (int dt = 0; dt < 4; ++dt) {
        #pragma unroll
        for (int r = 0; r < 4; ++r) {
            int d = wd * 64 + dt * 16 + kgrp * 4 + r;
            float* rowp = ctxp + obase + (size_t)d * Dd + we * 128 + l15;
            #pragma unroll
            for (int et = 0; et < 8; ++et)
                rowp[et * 16] = acc[dt][et][r];
        }
    }
}

// K3 slow (fallback): recompute staging from x1/x2 + stats.
__global__ __launch_bounds__(512, 2) void mg_k3_slow(const float* __restrict__ x1, const float* __restrict__ x2,
                                                     const float* __restrict__ g1, const float* __restrict__ b1,
                                                     float* __restrict__ ws, int nks)
{
    __shared__ ushort PA[256 * 64];
    __shared__ ushort PB[256 * 64];
    const float* mu1   = ws + OFF_MU1;
    const float* rstd1 = ws + OFF_RSTD1;
    const float* mu2   = ws + OFF_MU2;
    const float* rstd2 = ws + OFF_RSTD2;
    float* ctxp = ws + OFF_CTXP;

    int t = threadIdx.x;
    int ks_i = blockIdx.x % nks;
    int b = blockIdx.x / nks;
    int krange = Nn / nks;
    int ntiles = krange >> 6;
    int n_base = ks_i * krange;

    int o  = t >> 6;
    int c4 = t & 63;

    f32x4 g1v = ((const f32x4*)g1)[c4];
    f32x4 b1v = ((const f32x4*)b1)[c4];

    int lane = t & 63, wave = t >> 6;
    int wd = wave & 3, we = wave >> 2;
    int l15 = lane & 15, kgrp = lane >> 4;

    f32x4 acc[4][8];
    #pragma unroll
    for (int dt = 0; dt < 4; ++dt)
        #pragma unroll
        for (int et = 0; et < 8; ++et) acc[dt][et] = (f32x4){0.f, 0.f, 0.f, 0.f};

    for (int st = 0; st < ntiles; ++st) {
        int rowb = b * Nn + n_base + st * 64 + o * 8;
        __syncthreads();
        {
            f32x4 mv0 = *(const f32x4*)(mu1 + rowb),   mv1 = *(const f32x4*)(mu1 + rowb + 4);
            f32x4 rv0 = *(const f32x4*)(rstd1 + rowb), rv1 = *(const f32x4*)(rstd1 + rowb + 4);
            float mva[8] = {mv0[0], mv0[1], mv0[2], mv0[3], mv1[0], mv1[1], mv1[2], mv1[3]};
            float rva[8] = {rv0[0], rv0[1], rv0[2], rv0[3], rv1[0], rv1[1], rv1[2], rv1[3]};
            f32x4 xv[8];
            #pragma unroll
            for (int rr = 0; rr < 8; ++rr)
                xv[rr] = ((const f32x4*)x1)[(size_t)(rowb + rr) * 64 + c4];
            #pragma unroll
            for (int i = 0; i < 4; ++i) {
                int ch = c4 * 4 + i;
                ushort8 u;
                #pragma unroll
                for (int rr = 0; rr < 8; ++rr)
                    u[rr] = f2bf((xv[rr][i] - mva[rr]) * rva[rr] * g1v[i] + b1v[i]);
                *(ushort8*)&PB[ch * 64 + ((o + SWZ(ch)) & 7) * 8] = u;
            }
        }
        {
            f32x4 mv0 = *(const f32x4*)(mu2 + rowb),   mv1 = *(const f32x4*)(mu2 + rowb + 4);
            f32x4 rv0 = *(const f32x4*)(rstd2 + rowb), rv1 = *(const f32x4*)(rstd2 + rowb + 4);
            float mva[8] = {mv0[0], mv0[1], mv0[2], mv0[3], mv1[0], mv1[1], mv1[2], mv1[3]};
            float rva[8] = {rv0[0], rv0[1], rv0[2], rv0[3], rv1[0], rv1[1], rv1[2], rv1[3]};
            f32x4 xv[8];
            #pragma unroll
            for (int rr = 0; rr < 8; ++rr)
                xv[rr] = ((const f32x4*)x2)[(size_t)(rowb + rr) * 64 + c4];
            #pragma unroll
            for (int i = 0; i < 4; ++i) {
                int ch = c4 * 4 + i;
                ushort8 u;
                #pragma unroll
                for (int rr = 0; rr < 8; ++rr)
                    u[rr] = f2bf(__expf((xv[rr][i] - mva[rr]) * rva[rr] * g1v[i] + b1v[i]));
                *(ushort8*)&PA[ch * 64 + ((o + SWZ(ch)) & 7) * 8] = u;
            }
        }
        __syncthreads();

        #pragma unroll
        for (int kk = 0; kk < 2; ++kk) {
            short8 af[4], bf[8];
            #pragma unroll
            for (int dt = 0; dt < 4; ++dt) {
                int ch = wd * 64 + dt * 16 + l15;
                af[dt] = *(const short8*)&PA[ch * 64 + (((kk << 2) + kgrp + SWZ(ch)) & 7) * 8];
            }
            #pragma unroll
            for (int et = 0; et < 8; ++et) {
                int ch = we * 128 + et * 16 + l15;
                bf[et] = *(const short8*)&PB[ch * 64 + (((kk << 2) + kgrp + SWZ(ch)) & 7) * 8];
            }
            #pragma unroll
            for (int dt = 0; dt < 4; ++dt)
                #pragma unroll
                for (int et = 0; et < 8; ++et)
                    acc[dt][et] = __builtin_amdgcn_mfma_f32_16x16x32_bf16(af[dt], bf[et], acc[dt][et], 0, 0, 0);
        }
    }

    size_t obase = ((size_t)ks_i * Bc + b) * (Dd * Dd);
    #pragma unroll
    for (int dt = 0; dt < 4; ++dt) {
        #pragma unroll
        for (int r = 0; r < 4; ++r) {
            int d = wd * 64 + dt * 16 + kgrp * 4 + r;
            float* rowp = ctxp + obase + (size_t)d * Dd + we * 128 + l15;
            #pragma unroll
            for (int et = 0; et < 8; ++et)
                rowp[et * 16] = acc[dt][et][r];
        }
    }
}

// K5: reduce ctx partials, scale by 1/colsum, bitonic sort (desc), 4 top-k thresholds,
// combined masked softmax M = sum_i a_i * softmax_masked_i.  grid = B*D rows.
__global__ __launch_bounds__(256) void mg_k5_mask(const float* __restrict__ a1p, const float* __restrict__ a2p,
                                                  const float* __restrict__ a3p, const float* __restrict__ a4p,
                                                  float* __restrict__ ws, int nks)
{
    const float* ctxp   = ws + OFF_CTXP;
    const float* colsum = ws + OFF_COLSUM;
    float* Mo = ws + OFF_M;
    int t = threadIdx.x;
    int b = blockIdx.x >> 8, d = blockIdx.x & 255;
    __shared__ float s[256];
    __shared__ float wred[4][4];

    float c = 0.f;
    for (int p = 0; p < nks; ++p)
        c += ctxp[((size_t)p * Bc + b) * (Dd * Dd) + (size_t)d * Dd + t];
    float inv = 1.f / colsum[b * Dd + d];
    c *= inv;
    s[t] = c;
    __syncthreads();
    for (int k = 2; k <= 256; k <<= 1) {
        for (int j = k >> 1; j > 0; j >>= 1) {
            int ixj = t ^ j;
            if (ixj > t) {
                float A = s[t], Bv = s[ixj];
                bool desc = ((t & k) == 0);
                bool sw = desc ? (A < Bv) : (A > Bv);
                if (sw) { s[t] = Bv; s[ixj] = A; }
            }
            __syncthreads();
        }
    }
    float cmax = s[0];
    float t0 = s[127], t1 = s[169], t2 = s[191], t3 = s[203];  // k-1 for k = 128,170,192,204
    float e = __expf(c - cmax);
    float w0 = (c >= t0) ? e : 0.f;
    float w1 = (c >= t1) ? e : 0.f;
    float w2 = (c >= t2) ? e : 0.f;
    float w3 = (c >= t3) ? e : 0.f;
    float v0 = w0, v1 = w1, v2 = w2, v3 = w3;
    #pragma unroll
    for (int m = 1; m < 64; m <<= 1) {
        v0 += __shfl_xor(v0, m); v1 += __shfl_xor(v1, m);
        v2 += __shfl_xor(v2, m); v3 += __shfl_xor(v3, m);
    }
    int lane = t & 63, wv = t >> 6;
    if (lane == 0) { wred[wv][0] = v0; wred[wv][1] = v1; wred[wv][2] = v2; wred[wv][3] = v3; }
    __syncthreads();
    float S0 = wred[0][0] + wred[1][0] + wred[2][0] + wred[3][0];
    float S1 = wred[0][1] + wred[1][1] + wred[2][1] + wred[3][1];
    float S2 = wred[0][2] + wred[1][2] + wred[2][2] + wred[3][2];
    float S3 = wred[0][3] + wred[1][3] + wred[2][3] + wred[3][3];
    float Mv = a1p[0] * (w0 / S0) + a2p[0] * (w1 / S1) + a3p[0] * (w2 / S2) + a4p[0] * (w3 / S3);
    Mo[(b * Dd + d) * Dd + t] = Mv;
}

// K6: W2 bf16 in FRAG-LINEAR layout for K7's LDS staging.
__global__ __launch_bounds__(256) void mg_k6_w2(const float* __restrict__ Wr, float* __restrict__ ws)
{
    const float* Mo = ws + OFF_M;
    ushort* W2B = (ushort*)(ws + OFF_W2T);
    __shared__ float Mt[32][128];
    __shared__ float WrT[32][36];
    int t = threadIdx.x;
    int b = blockIdx.x >> 5, ob = (blockIdx.x >> 1) & 15, eh = blockIdx.x & 1;
    int o0 = ob * 32, e0 = eh * 128;
    int ol4 = t & 7, el = t >> 3;
    float acc[4][4];
    #pragma unroll
    for (int i = 0; i < 4; ++i)
        #pragma unroll
        for (int j = 0; j < 4; ++j) acc[i][j] = 0.f;

    for (int ch = 0; ch < 8; ++ch) {
        int c0 = ch * 32;
        __syncthreads();
        #pragma unroll
        for (int k = 0; k < 4; ++k) {
            int fi = t + k * 256;
            int row = fi >> 5, c4 = fi & 31;
            float4 mv = ((const float4*)Mo)[(b * Dd + c0 + row) * 64 + (e0 >> 2) + c4];
            *(float4*)&Mt[row][c4 * 4] = mv;
        }
        {
            int ol = t >> 3, c4 = t & 7;
            float4 wv = ((const float4*)Wr)[(o0 + ol) * 64 + (c0 >> 2) + c4];
            WrT[c4 * 4 + 0][ol] = wv.x;
            WrT[c4 * 4 + 1][ol] = wv.y;
            WrT[c4 * 4 + 2][ol] = wv.z;
            WrT[c4 * 4 + 3][ol] = wv.w;
        }
        __syncthreads();
        #pragma unroll
        for (int cc = 0; cc < 32; ++cc) {
            float4 w4 = *(const float4*)&WrT[cc][ol4 * 4];
            float4 m4 = *(const float4*)&Mt[cc][el * 4];
            float wv[4] = {w4.x, w4.y, w4.z, w4.w};
            float mv[4] = {m4.x, m4.y, m4.z, m4.w};
            #pragma unroll
            for (int i = 0; i < 4; ++i)
                #pragma unroll
                for (int j = 0; j < 4; ++j)
                    acc[i][j] = fmaf(wv[i], mv[j], acc[i][j]);
        }
    }
    {
        int e_base = e0 + el * 4;
        int ks = e_base >> 5;
        int kg = (e_base >> 3) & 3, jj = e_base & 7;   // jj in {0,4}
        #pragma unroll
        for (int i = 0; i < 4; ++i) {
            int o = o0 + ol4 * 4 + i;
            int wv2 = o >> 6, ot = (o >> 4) & 3, cA = o & 15;
            ushort4 u;
            u.x = f2bf(acc[i][0]); u.y = f2bf(acc[i][1]);
            u.z = f2bf(acc[i][2]); u.w = f2bf(acc[i][3]);
            size_t idx = ((size_t)b * 8 + ks) * 16384 + wv2 * 2048 + ot * 512
                       + (kg * 16 + cA) * 8 + jj;
            *(ushort4*)&W2B[idx] = u;
        }
    }
}

// K7 v8 (gload_lds 2-phase, proven R13): unchanged.
__global__ __launch_bounds__(512) void mg_k7_final(const float* __restrict__ x2,
        const float* __restrict__ g1, const float* __restrict__ b1,
        const float* __restrict__ br, const float* __restrict__ g2, const float* __restrict__ b2,
        const float* __restrict__ ws, float* __restrict__ out)
{
    __shared__ ushort smem[8192 + 2 * 16384];   // qsT 16KB + W2 dbuf 64KB = 80KB
    ushort* qsT = smem;
    ushort* W0 = smem + 8192;
    ushort* W1 = smem + 8192 + 16384;

    const float* mu2    = ws + OFF_MU2;
    const float* rstd2  = ws + OFF_RSTD2;
    const float* rowinv = ws + OFF_ROWINV;
    const ushort* W2B   = (const ushort*)(ws + OFF_W2T);

    int t = threadIdx.x;
    int b = blockIdx.x / 288, nt0 = blockIdx.x % 288;
    int n0 = nt0 * 32;
    int lw = t & 63, wave = t >> 6;
    int colA = lw & 15, kgrp = lw >> 4;

#define STAGEW(dstbuf, ksv)                                                        \
    {                                                                              \
        size_t so_ = ((size_t)b * 8 + (ksv)) * 16384 + wave * 2048;                \
        _Pragma("unroll")                                                          \
        for (int k_ = 0; k_ < 4; ++k_) {                                           \
            __builtin_amdgcn_global_load_lds(                                      \
                (const __attribute__((address_space(1))) unsigned int*)            \
                    (W2B + so_ + k_ * 512 + lw * 8),                               \
                (__attribute__((address_space(3))) unsigned int*)                  \
                    ((dstbuf) + wave * 2048 + k_ * 512),                           \
                16, 0, 0);                                                         \
        }                                                                          \
    }

    STAGEW(W0, 0);

    {
        int row = t >> 4, gpair = (t & 15) * 2;
        int ni = b * Nn + n0 + row;
        float m = mu2[ni], r = rstd2[ni], ri = rowinv[ni];
        #pragma unroll
        for (int jj = 0; jj < 2; ++jj) {
            int g = gpair + jj;
            const float4* xp = (const float4*)x2 + (size_t)ni * 64 + g * 2;
            float4 xa = xp[0], xb = xp[1];
            float4 ga = ((const float4*)g1)[g * 2], gc = ((const float4*)g1)[g * 2 + 1];
            float4 ba = ((const float4*)b1)[g * 2], bc = ((const float4*)b1)[g * 2 + 1];
            float v[8]  = {xa.x, xa.y, xa.z, xa.w, xb.x, xb.y, xb.z, xb.w};
            float gv[8] = {ga.x, ga.y, ga.z, ga.w, gc.x, gc.y, gc.z, gc.w};
            float bv[8] = {ba.x, ba.y, ba.z, ba.w, bc.x, bc.y, bc.z, bc.w};
            ushort8 u;
            #pragma unroll
            for (int q = 0; q < 8; ++q)
                u[q] = f2bf(__expf((v[q] - m) * r * gv[q] + bv[q]) * ri);
            *(ushort8*)&qsT[row * 256 + ((g ^ (row & 7)) << 3)] = u;
        }
    }
    __syncthreads();

    f32x4 acc[4][2];
    #pragma unroll
    for (int ot = 0; ot < 4; ++ot) {
        acc[ot][0] = (f32x4){0.f, 0.f, 0.f, 0.f};
        acc[ot][1] = (f32x4){0.f, 0.f, 0.f, 0.f};
    }

    #pragma unroll
    for (int ks = 0; ks < 8; ++ks) {
        if (ks < 7) {
            if ((ks & 1) == 0) { STAGEW(W1, ks + 1); }
            else               { STAGEW(W0, ks + 1); }
        }
        const ushort* wb = (ks & 1) ? W1 : W0;
        int gsl = ((ks * 4 + kgrp) ^ (colA & 7)) << 3;
        short8 bf0 = *(const short8*)&qsT[colA * 256 + gsl];
        short8 bf1 = *(const short8*)&qsT[(16 + colA) * 256 + gsl];
        #pragma unroll
        for (int ot = 0; ot < 4; ++ot) {
            short8 af = *(const short8*)&wb[wave * 2048 + ot * 512 + lw * 8];
            acc[ot][0] = __builtin_amdgcn_mfma_f32_16x16x32_bf16(af, bf0, acc[ot][0], 0, 0, 0);
            acc[ot][1] = __builtin_amdgcn_mfma_f32_16x16x32_bf16(af, bf1, acc[ot][1], 0, 0, 0);
        }
        __syncthreads();
    }
#undef STAGEW

    float (*stat)[2][16][2] = (float (*)[2][16][2])(void*)smem;
    float (*musig)[2] = (float (*)[2])((float*)(void*)smem + 512);

    float ps[2] = {0.f, 0.f}, pq[2] = {0.f, 0.f};
    #pragma unroll
    for (int ot = 0; ot < 4; ++ot) {
        #pragma unroll
        for (int r = 0; r < 4; ++r) {
            int o = wave * 64 + ot * 16 + kgrp * 4 + r;
            float bb = br[o];
            float v0 = acc[ot][0][r] + bb;
            float v1 = acc[ot][1][r] + bb;
            acc[ot][0][r] = v0; acc[ot][1][r] = v1;
            ps[0] += v0; pq[0] += v0 * v0;
            ps[1] += v1; pq[1] += v1 * v1;
        }
    }
    #pragma unroll
    for (int m = 16; m <= 32; m <<= 1) {
        ps[0] += __shfl_xor(ps[0], m); pq[0] += __shfl_xor(pq[0], m);
        ps[1] += __shfl_xor(ps[1], m); pq[1] += __shfl_xor(pq[1], m);
    }
    if (lw < 16) {
        stat[wave][0][lw][0] = ps[0]; stat[wave][0][lw][1] = pq[0];
        stat[wave][1][lw][0] = ps[1]; stat[wave][1][lw][1] = pq[1];
    }
    __syncthreads();
    if (t < 32) {
        int ntl = t >> 4, col = t & 15;
        float S = 0.f, Q = 0.f;
        #pragma unroll
        for (int w2 = 0; w2 < 8; ++w2) { S += stat[w2][ntl][col][0]; Q += stat[w2][ntl][col][1]; }
        float mu = S * (1.f / Oo);
        float var = Q * (1.f / Oo) - mu * mu;
        musig[t][0] = mu;
        musig[t][1] = rsqrtf(var + EPSc);
    }
    __syncthreads();

    float mn0 = musig[colA][0],      rs0 = musig[colA][1];
    float mn1 = musig[16 + colA][0], rs1 = musig[16 + colA][1];
    #pragma unroll
    for (int ot = 0; ot < 4; ++ot) {
        #pragma unroll
        for (int r = 0; r < 4; ++r) {
            int o = wave * 64 + ot * 16 + kgrp * 4 + r;
            float gg = g2[o], bb2 = b2[o];
            size_t ob = ((size_t)b * Oo + o) * Nn + n0;
            out[ob + colA]      = (acc[ot][0][r] - mn0) * rs0 * gg + bb2;
            out[ob + 16 + colA] = (acc[ot][1][r] - mn1) * rs1 * gg + bb2;
        }
    }
}

extern "C" void kernel_launch(void* const* d_in, const int* in_sizes, int n_in,
                              void* d_out, int out_size, void* d_ws, size_t ws_size,
                              hipStream_t stream)
{
    (void)in_sizes; (void)n_in; (void)out_size;
    const float* x1 = (const float*)d_in[0];
    const float* x2 = (const float*)d_in[1];
    const float* g1 = (const float*)d_in[2];
    const float* b1 = (const float*)d_in[3];
    const float* Wr = (const float*)d_in[4];
    const float* br = (const float*)d_in[5];
    const float* g2 = (const float*)d_in[6];
    const float* b2 = (const float*)d_in[7];
    const float* a1 = (const float*)d_in[8];
    const float* a2 = (const float*)d_in[9];
    const float* a3 = (const float*)d_in[10];
    const float* a4 = (const float*)d_in[11];
    float* ws = (float*)d_ws;
    float* out = (float*)d_out;

    int fast = ((size_t)WS_FAST_END * 4ull <= ws_size) ? 1 : 0;
    int nks;
    if (fast) {
        nks = 24;
    } else {
        const int cand[6] = {24, 16, 12, 8, 4, 2};
        nks = 2;
        for (int ci = 0; ci < 6; ++ci) {
            if (((size_t)OFF_CTXP + (size_t)cand[ci] * 524288ull) * 4ull <= ws_size) { nks = cand[ci]; break; }
        }
    }

    hipLaunchKernelGGL(mg_k0_zero, dim3(2), dim3(256), 0, stream, ws + OFF_COLSUM, 512);
    hipLaunchKernelGGL(mg_k1_stats, dim3(1152), dim3(256), 0, stream, x1, x2, g1, b1, ws, fast);
    if (fast) {
        hipLaunchKernelGGL(mg_k3_ctx_f, dim3(Bc * 24), dim3(512), 0, stream, ws);
    } else {
        hipLaunchKernelGGL(mg_k3_slow, dim3(Bc * nks), dim3(512), 0, stream, x1, x2, g1, b1, ws, nks);
    }
    hipLaunchKernelGGL(mg_k5_mask, dim3(2048), dim3(256), 0, stream, a1, a2, a3, a4, ws, nks);
    hipLaunchKernelGGL(mg_k6_w2, dim3(256), dim3(256), 0, stream, Wr, ws);
    hipLaunchKernelGGL(mg_k7_final, dim3(2304), dim3(512), 0, stream, x2, g1, b1, br, g2, b2, ws, out);
}

// Round 16
// 194.899 us; speedup vs baseline: 1.2527x; 1.2527x over previous
//
#include <hip/hip_runtime.h>
#include <hip/hip_bf16.h>

#define Bc 8
#define Nn 9216
#define Dd 256
#define Oo 512
#define EPSc 1e-5f

// workspace float offsets
#define OFF_MU1    0          // 73728
#define OFF_RSTD1  73728
#define OFF_MU2    147456
#define OFF_RSTD2  221184
#define OFF_ROWINV 294912
#define OFF_COLSUM 368640     // 2048
#define OFF_M      370688     // 524288
#define OFF_W2T    894976     // W2 bf16 frag-linear: 1,048,576 ushorts
#define OFF_CTXP   1419264    // nks * 524288 floats of ctx partials (adaptive)

typedef __attribute__((ext_vector_type(4))) float f32x4;
typedef __attribute__((ext_vector_type(8))) short short8;
typedef __attribute__((ext_vector_type(8))) unsigned short ushort8;

static __device__ __forceinline__ unsigned short f2bf(float f) {
    __hip_bfloat16 h = __float2bfloat16(f);
    union { __hip_bfloat16 hh; unsigned short uu; } cv; cv.hh = h;
    return cv.uu;
}

// granule swizzle for channel-major bf16 tiles [ch][64n]: write conflict-free, read ~2-way
#define SWZ(ch) (((((ch) >> 2) & 7)) ^ ((((ch) & 3)) << 1))

__global__ __launch_bounds__(256) void mg_k0_zero(float* __restrict__ p, int n4) {
    int i = blockIdx.x * 256 + threadIdx.x;
    if (i < n4) ((float4*)p)[i] = make_float4(0.f, 0.f, 0.f, 0.f);
}

// K1: one pass over x1,x2. Per row: LN stats for both; query row-sumexp; col-sumexp partials -> atomics.
__global__ __launch_bounds__(256) void mg_k1_stats(const float* __restrict__ x1, const float* __restrict__ x2,
                                                   const float* __restrict__ g1, const float* __restrict__ b1,
                                                   float* __restrict__ ws)
{
    float* mu1    = ws + OFF_MU1;
    float* rstd1  = ws + OFF_RSTD1;
    float* mu2    = ws + OFF_MU2;
    float* rstd2  = ws + OFF_RSTD2;
    float* rowinv = ws + OFF_ROWINV;
    float* colsum = ws + OFF_COLSUM;

    int t = threadIdx.x, lane = t & 63, w = t >> 6;
    int b = blockIdx.x / 144, rb = blockIdx.x % 144;
    int nbase = rb * 64;

    float4 g1v = ((const float4*)g1)[lane];
    float4 b1v = ((const float4*)b1)[lane];
    float cs0 = 0.f, cs1 = 0.f, cs2 = 0.f, cs3 = 0.f;
    __shared__ float csL[4][256];

    for (int i = 0; i < 16; ++i) {
        int n = nbase + i * 4 + w;
        int base = (b * Nn + n) * 64 + lane;
        float4 xa = ((const float4*)x1)[base];
        float4 xb = ((const float4*)x2)[base];
        float s1 = xa.x + xa.y + xa.z + xa.w;
        float q1 = xa.x*xa.x + xa.y*xa.y + xa.z*xa.z + xa.w*xa.w;
        float s2 = xb.x + xb.y + xb.z + xb.w;
        float q2 = xb.x*xb.x + xb.y*xb.y + xb.z*xb.z + xb.w*xb.w;
        #pragma unroll
        for (int m = 1; m < 64; m <<= 1) {
            s1 += __shfl_xor(s1, m); q1 += __shfl_xor(q1, m);
            s2 += __shfl_xor(s2, m); q2 += __shfl_xor(q2, m);
        }
        float m1 = s1 * (1.f / Dd), m2 = s2 * (1.f / Dd);
        float r1 = rsqrtf(q1 * (1.f / Dd) - m1 * m1 + EPSc);
        float r2 = rsqrtf(q2 * (1.f / Dd) - m2 * m2 + EPSc);
        int ni = b * Nn + n;
        if (lane == 0) { mu1[ni] = m1; rstd1[ni] = r1; mu2[ni] = m2; rstd2[ni] = r2; }
        // LN(x2) values are bounded -> exp without max-subtraction is safe in f32
        float e0 = __expf((xb.x - m2) * r2 * g1v.x + b1v.x);
        float e1 = __expf((xb.y - m2) * r2 * g1v.y + b1v.y);
        float e2 = __expf((xb.z - m2) * r2 * g1v.z + b1v.z);
        float e3 = __expf((xb.w - m2) * r2 * g1v.w + b1v.w);
        float rs = e0 + e1 + e2 + e3;
        #pragma unroll
        for (int m = 1; m < 64; m <<= 1) rs += __shfl_xor(rs, m);
        if (lane == 0) rowinv[ni] = 1.f / rs;
        cs0 += e0; cs1 += e1; cs2 += e2; cs3 += e3;
    }
    csL[w][lane * 4 + 0] = cs0;
    csL[w][lane * 4 + 1] = cs1;
    csL[w][lane * 4 + 2] = cs2;
    csL[w][lane * 4 + 3] = cs3;
    __syncthreads();
    float tot = csL[0][t] + csL[1][t] + csL[2][t] + csL[3][t];
    atomicAdd(&colsum[b * Dd + t], tot);
}

// K3 (MFMA): ctx_partial[p][b][d][e] = sum_{n in slice p} exp(n2[n][d]) * n1[n][e]
// grid: b(8) x ks(nks); block 512 thr (8 waves), tile 256d x 256e, K-tile 64 n.
__global__ __launch_bounds__(512, 2) void mg_k3_ctx(const float* __restrict__ x1, const float* __restrict__ x2,
                                                    const float* __restrict__ g1, const float* __restrict__ b1,
                                                    float* __restrict__ ws, int nks)
{
    __shared__ ushort PA[256 * 64];   // exp(n2): [d][n]
    __shared__ ushort PB[256 * 64];   // n1:      [e][n]
    const float* mu1   = ws + OFF_MU1;
    const float* rstd1 = ws + OFF_RSTD1;
    const float* mu2   = ws + OFF_MU2;
    const float* rstd2 = ws + OFF_RSTD2;
    float* ctxp = ws + OFF_CTXP;

    int t = threadIdx.x;
    int ks_i = blockIdx.x % nks;
    int b = blockIdx.x / nks;
    int krange = Nn / nks;
    int ntiles = krange >> 6;
    int n_base = ks_i * krange;

    int o  = t >> 6;
    int c4 = t & 63;

    f32x4 g1v = ((const f32x4*)g1)[c4];
    f32x4 b1v = ((const f32x4*)b1)[c4];

    int lane = t & 63, wave = t >> 6;
    int wd = wave & 3, we = wave >> 2;
    int l15 = lane & 15, kgrp = lane >> 4;

    f32x4 acc[4][8];
    #pragma unroll
    for (int dt = 0; dt < 4; ++dt)
        #pragma unroll
        for (int et = 0; et < 8; ++et) acc[dt][et] = (f32x4){0.f, 0.f, 0.f, 0.f};

    for (int st = 0; st < ntiles; ++st) {
        int rowb = b * Nn + n_base + st * 64 + o * 8;
        __syncthreads();
        {
            f32x4 mv0 = *(const f32x4*)(mu1 + rowb),   mv1 = *(const f32x4*)(mu1 + rowb + 4);
            f32x4 rv0 = *(const f32x4*)(rstd1 + rowb), rv1 = *(const f32x4*)(rstd1 + rowb + 4);
            float mva[8] = {mv0[0], mv0[1], mv0[2], mv0[3], mv1[0], mv1[1], mv1[2], mv1[3]};
            float rva[8] = {rv0[0], rv0[1], rv0[2], rv0[3], rv1[0], rv1[1], rv1[2], rv1[3]};
            f32x4 xv[8];
            #pragma unroll
            for (int rr = 0; rr < 8; ++rr)
                xv[rr] = ((const f32x4*)x1)[(size_t)(rowb + rr) * 64 + c4];
            #pragma unroll
            for (int i = 0; i < 4; ++i) {
                int ch = c4 * 4 + i;
                ushort8 u;
                #pragma unroll
                for (int rr = 0; rr < 8; ++rr)
                    u[rr] = f2bf((xv[rr][i] - mva[rr]) * rva[rr] * g1v[i] + b1v[i]);
                *(ushort8*)&PB[ch * 64 + ((o + SWZ(ch)) & 7) * 8] = u;
            }
        }
        {
            f32x4 mv0 = *(const f32x4*)(mu2 + rowb),   mv1 = *(const f32x4*)(mu2 + rowb + 4);
            f32x4 rv0 = *(const f32x4*)(rstd2 + rowb), rv1 = *(const f32x4*)(rstd2 + rowb + 4);
            float mva[8] = {mv0[0], mv0[1], mv0[2], mv0[3], mv1[0], mv1[1], mv1[2], mv1[3]};
            float rva[8] = {rv0[0], rv0[1], rv0[2], rv0[3], rv1[0], rv1[1], rv1[2], rv1[3]};
            f32x4 xv[8];
            #pragma unroll
            for (int rr = 0; rr < 8; ++rr)
                xv[rr] = ((const f32x4*)x2)[(size_t)(rowb + rr) * 64 + c4];
            #pragma unroll
            for (int i = 0; i < 4; ++i) {
                int ch = c4 * 4 + i;
                ushort8 u;
                #pragma unroll
                for (int rr = 0; rr < 8; ++rr)
                    u[rr] = f2bf(__expf((xv[rr][i] - mva[rr]) * rva[rr] * g1v[i] + b1v[i]));
                *(ushort8*)&PA[ch * 64 + ((o + SWZ(ch)) & 7) * 8] = u;
            }
        }
        __syncthreads();

        #pragma unroll
        for (int kk = 0; kk < 2; ++kk) {
            short8 af[4], bf[8];
            #pragma unroll
            for (int dt = 0; dt < 4; ++dt) {
                int ch = wd * 64 + dt * 16 + l15;
                af[dt] = *(const short8*)&PA[ch * 64 + (((kk << 2) + kgrp + SWZ(ch)) & 7) * 8];
            }
            #pragma unroll
            for (int et = 0; et < 8; ++et) {
                int ch = we * 128 + et * 16 + l15;
                bf[et] = *(const short8*)&PB[ch * 64 + (((kk << 2) + kgrp + SWZ(ch)) & 7) * 8];
            }
            #pragma unroll
            for (int dt = 0; dt < 4; ++dt)
                #pragma unroll
                for (int et = 0; et < 8; ++et)
                    acc[dt][et] = __builtin_amdgcn_mfma_f32_16x16x32_bf16(af[dt], bf[et], acc[dt][et], 0, 0, 0);
        }
    }

    size_t obase = ((size_t)ks_i * Bc + b) * (Dd * Dd);
    #pragma unroll
    for (int dt = 0; dt < 4; ++dt) {
        #pragma unroll
        for (int r = 0; r < 4; ++r) {
            int d = wd * 64 + dt * 16 + kgrp * 4 + r;
            float* rowp = ctxp + obase + (size_t)d * Dd + we * 128 + l15;
            #pragma unroll
            for (int et = 0; et < 8; ++et)
                rowp[et * 16] = acc[dt][et][r];
        }
    }
}

// K5: reduce ctx partials, scale by 1/colsum, bitonic sort (desc), 4 top-k thresholds,
// combined masked softmax M = sum_i a_i * softmax_masked_i.  grid = B*D rows.
__global__ __launch_bounds__(256) void mg_k5_mask(const float* __restrict__ a1p, const float* __restrict__ a2p,
                                                  const float* __restrict__ a3p, const float* __restrict__ a4p,
                                                  float* __restrict__ ws, int nks)
{
    const float* ctxp   = ws + OFF_CTXP;
    const float* colsum = ws + OFF_COLSUM;
    float* Mo = ws + OFF_M;
    int t = threadIdx.x;
    int b = blockIdx.x >> 8, d = blockIdx.x & 255;
    __shared__ float s[256];
    __shared__ float wred[4][4];

    float c = 0.f;
    for (int p = 0; p < nks; ++p)
        c += ctxp[((size_t)p * Bc + b) * (Dd * Dd) + (size_t)d * Dd + t];
    float inv = 1.f / colsum[b * Dd + d];
    c *= inv;
    s[t] = c;
    __syncthreads();
    for (int k = 2; k <= 256; k <<= 1) {
        for (int j = k >> 1; j > 0; j >>= 1) {
            int ixj = t ^ j;
            if (ixj > t) {
                float A = s[t], Bv = s[ixj];
                bool desc = ((t & k) == 0);
                bool sw = desc ? (A < Bv) : (A > Bv);
                if (sw) { s[t] = Bv; s[ixj] = A; }
            }
            __syncthreads();
        }
    }
    float cmax = s[0];
    float t0 = s[127], t1 = s[169], t2 = s[191], t3 = s[203];  // k-1 for k = 128,170,192,204
    float e = __expf(c - cmax);
    float w0 = (c >= t0) ? e : 0.f;
    float w1 = (c >= t1) ? e : 0.f;
    float w2 = (c >= t2) ? e : 0.f;
    float w3 = (c >= t3) ? e : 0.f;
    float v0 = w0, v1 = w1, v2 = w2, v3 = w3;
    #pragma unroll
    for (int m = 1; m < 64; m <<= 1) {
        v0 += __shfl_xor(v0, m); v1 += __shfl_xor(v1, m);
        v2 += __shfl_xor(v2, m); v3 += __shfl_xor(v3, m);
    }
    int lane = t & 63, wv = t >> 6;
    if (lane == 0) { wred[wv][0] = v0; wred[wv][1] = v1; wred[wv][2] = v2; wred[wv][3] = v3; }
    __syncthreads();
    float S0 = wred[0][0] + wred[1][0] + wred[2][0] + wred[3][0];
    float S1 = wred[0][1] + wred[1][1] + wred[2][1] + wred[3][1];
    float S2 = wred[0][2] + wred[1][2] + wred[2][2] + wred[3][2];
    float S3 = wred[0][3] + wred[1][3] + wred[2][3] + wred[3][3];
    float Mv = a1p[0] * (w0 / S0) + a2p[0] * (w1 / S1) + a3p[0] * (w2 / S2) + a4p[0] * (w3 / S3);
    Mo[(b * Dd + d) * Dd + t] = Mv;
}

// K6: W2 bf16 in FRAG-LINEAR layout for K7's LDS staging:
// ushort idx = ((b*8+ks)*16384) + wave*2048 + ot*512 + (kgrp*16+colA)*8 + j
// where o = wave*64+ot*16+colA, e = ks*32+kgrp*8+j.
__global__ __launch_bounds__(256) void mg_k6_w2(const float* __restrict__ Wr, float* __restrict__ ws)
{
    const float* Mo = ws + OFF_M;
    ushort* W2B = (ushort*)(ws + OFF_W2T);
    __shared__ float Mt[32][128];
    __shared__ float WrT[32][36];
    int t = threadIdx.x;
    int b = blockIdx.x >> 5, ob = (blockIdx.x >> 1) & 15, eh = blockIdx.x & 1;
    int o0 = ob * 32, e0 = eh * 128;
    int ol4 = t & 7, el = t >> 3;
    float acc[4][4];
    #pragma unroll
    for (int i = 0; i < 4; ++i)
        #pragma unroll
        for (int j = 0; j < 4; ++j) acc[i][j] = 0.f;

    for (int ch = 0; ch < 8; ++ch) {
        int c0 = ch * 32;
        __syncthreads();
        #pragma unroll
        for (int k = 0; k < 4; ++k) {
            int fi = t + k * 256;
            int row = fi >> 5, c4 = fi & 31;
            float4 mv = ((const float4*)Mo)[(b * Dd + c0 + row) * 64 + (e0 >> 2) + c4];
            *(float4*)&Mt[row][c4 * 4] = mv;
        }
        {
            int ol = t >> 3, c4 = t & 7;
            float4 wv = ((const float4*)Wr)[(o0 + ol) * 64 + (c0 >> 2) + c4];
            WrT[c4 * 4 + 0][ol] = wv.x;
            WrT[c4 * 4 + 1][ol] = wv.y;
            WrT[c4 * 4 + 2][ol] = wv.z;
            WrT[c4 * 4 + 3][ol] = wv.w;
        }
        __syncthreads();
        #pragma unroll
        for (int cc = 0; cc < 32; ++cc) {
            float4 w4 = *(const float4*)&WrT[cc][ol4 * 4];
            float4 m4 = *(const float4*)&Mt[cc][el * 4];
            float wv[4] = {w4.x, w4.y, w4.z, w4.w};
            float mv[4] = {m4.x, m4.y, m4.z, m4.w};
            #pragma unroll
            for (int i = 0; i < 4; ++i)
                #pragma unroll
                for (int j = 0; j < 4; ++j)
                    acc[i][j] = fmaf(wv[i], mv[j], acc[i][j]);
        }
    }
    {
        int e_base = e0 + el * 4;
        int ks = e_base >> 5;
        int kg = (e_base >> 3) & 3, jj = e_base & 7;   // jj in {0,4}
        #pragma unroll
        for (int i = 0; i < 4; ++i) {
            int o = o0 + ol4 * 4 + i;
            int wv2 = o >> 6, ot = (o >> 4) & 3, cA = o & 15;
            ushort4 u;
            u.x = f2bf(acc[i][0]); u.y = f2bf(acc[i][1]);
            u.z = f2bf(acc[i][2]); u.w = f2bf(acc[i][3]);
            size_t idx = ((size_t)b * 8 + ks) * 16384 + wv2 * 2048 + ot * 512
                       + (kg * 16 + cA) * 8 + jj;
            *(ushort4*)&W2B[idx] = u;
        }
    }
}

// K7 v9 (gload_lds, SINGLE-buffered W2, occupancy-first): 48 KB LDS -> 3 blocks/CU.
// Cross-block wave overlap (m114) hides stage latency; dbuf bought nothing since the
// barrier drains vmcnt(0) anyway, but cost 32 KB LDS (2 blocks/CU).
__global__ __launch_bounds__(512, 6) void mg_k7_final(const float* __restrict__ x2,
        const float* __restrict__ g1, const float* __restrict__ b1,
        const float* __restrict__ br, const float* __restrict__ g2, const float* __restrict__ b2,
        const float* __restrict__ ws, float* __restrict__ out)
{
    __shared__ ushort smem[8192 + 16384];   // qsT 16KB + W 32KB = 48KB
    ushort* qsT = smem;
    ushort* W = smem + 8192;

    const float* mu2    = ws + OFF_MU2;
    const float* rstd2  = ws + OFF_RSTD2;
    const float* rowinv = ws + OFF_ROWINV;
    const ushort* W2B   = (const ushort*)(ws + OFF_W2T);

    int t = threadIdx.x;
    int b = blockIdx.x / 288, nt0 = blockIdx.x % 288;
    int n0 = nt0 * 32;
    int lw = t & 63, wave = t >> 6;
    int colA = lw & 15, kgrp = lw >> 4;

#define STAGEW(ksv)                                                                \
    {                                                                              \
        size_t so_ = ((size_t)b * 8 + (ksv)) * 16384 + wave * 2048;                \
        _Pragma("unroll")                                                          \
        for (int k_ = 0; k_ < 4; ++k_) {                                           \
            __builtin_amdgcn_global_load_lds(                                      \
                (const __attribute__((address_space(1))) unsigned int*)            \
                    (W2B + so_ + k_ * 512 + lw * 8),                               \
                (__attribute__((address_space(3))) unsigned int*)                  \
                    (W + wave * 2048 + k_ * 512),                                  \
                16, 0, 0);                                                         \
        }                                                                          \
    }

    // issue ks=0 stage first so it flies under q staging
    STAGEW(0);

    // stage q^T: 32 rows x 256 e; thread: row = t>>4, granules (t&15)*2 .. +1
    {
        int row = t >> 4, gpair = (t & 15) * 2;
        int ni = b * Nn + n0 + row;
        float m = mu2[ni], r = rstd2[ni], ri = rowinv[ni];
        #pragma unroll
        for (int jj = 0; jj < 2; ++jj) {
            int g = gpair + jj;
            const float4* xp = (const float4*)x2 + (size_t)ni * 64 + g * 2;
            float4 xa = xp[0], xb = xp[1];
            float4 ga = ((const float4*)g1)[g * 2], gc = ((const float4*)g1)[g * 2 + 1];
            float4 ba = ((const float4*)b1)[g * 2], bc = ((const float4*)b1)[g * 2 + 1];
            float v[8]  = {xa.x, xa.y, xa.z, xa.w, xb.x, xb.y, xb.z, xb.w};
            float gv[8] = {ga.x, ga.y, ga.z, ga.w, gc.x, gc.y, gc.z, gc.w};
            float bv[8] = {ba.x, ba.y, ba.z, ba.w, bc.x, bc.y, bc.z, bc.w};
            ushort8 u;
            #pragma unroll
            for (int q = 0; q < 8; ++q)
                u[q] = f2bf(__expf((v[q] - m) * r * gv[q] + bv[q]) * ri);
            *(ushort8*)&qsT[row * 256 + ((g ^ (row & 7)) << 3)] = u;
        }
    }
    __syncthreads();   // drains vmcnt: W(ks=0) staged; qsT ready

    f32x4 acc[4][2];
    #pragma unroll
    for (int ot = 0; ot < 4; ++ot) {
        acc[ot][0] = (f32x4){0.f, 0.f, 0.f, 0.f};
        acc[ot][1] = (f32x4){0.f, 0.f, 0.f, 0.f};
    }

    #pragma unroll
    for (int ks = 0; ks < 8; ++ks) {
        int gsl = ((ks * 4 + kgrp) ^ (colA & 7)) << 3;
        short8 bf0 = *(const short8*)&qsT[colA * 256 + gsl];
        short8 bf1 = *(const short8*)&qsT[(16 + colA) * 256 + gsl];
        #pragma unroll
        for (int ot = 0; ot < 4; ++ot) {
            short8 af = *(const short8*)&W[wave * 2048 + ot * 512 + lw * 8];
            acc[ot][0] = __builtin_amdgcn_mfma_f32_16x16x32_bf16(af, bf0, acc[ot][0], 0, 0, 0);
            acc[ot][1] = __builtin_amdgcn_mfma_f32_16x16x32_bf16(af, bf1, acc[ot][1], 0, 0, 0);
        }
        if (ks < 7) {
            __syncthreads();    // all waves done reading W
            STAGEW(ks + 1);
            __syncthreads();    // drain stage
        }
    }
#undef STAGEW
    __syncthreads();   // last MFMA reads of qsT done before stat overlay

    // epilogue: +br, LN over 512 o per n-column, store transposed.
    float (*stat)[2][16][2] = (float (*)[2][16][2])(void*)smem;    // overlays dead qsT
    float (*musig)[2] = (float (*)[2])((float*)(void*)smem + 512);

    float ps[2] = {0.f, 0.f}, pq[2] = {0.f, 0.f};
    #pragma unroll
    for (int ot = 0; ot < 4; ++ot) {
        #pragma unroll
        for (int r = 0; r < 4; ++r) {
            int o = wave * 64 + ot * 16 + kgrp * 4 + r;
            float bb = br[o];
            float v0 = acc[ot][0][r] + bb;
            float v1 = acc[ot][1][r] + bb;
            acc[ot][0][r] = v0; acc[ot][1][r] = v1;
            ps[0] += v0; pq[0] += v0 * v0;
            ps[1] += v1; pq[1] += v1 * v1;
        }
    }
    #pragma unroll
    for (int m = 16; m <= 32; m <<= 1) {
        ps[0] += __shfl_xor(ps[0], m); pq[0] += __shfl_xor(pq[0], m);
        ps[1] += __shfl_xor(ps[1], m); pq[1] += __shfl_xor(pq[1], m);
    }
    if (lw < 16) {
        stat[wave][0][lw][0] = ps[0]; stat[wave][0][lw][1] = pq[0];
        stat[wave][1][lw][0] = ps[1]; stat[wave][1][lw][1] = pq[1];
    }
    __syncthreads();
    if (t < 32) {
        int ntl = t >> 4, col = t & 15;
        float S = 0.f, Q = 0.f;
        #pragma unroll
        for (int w2 = 0; w2 < 8; ++w2) { S += stat[w2][ntl][col][0]; Q += stat[w2][ntl][col][1]; }
        float mu = S * (1.f / Oo);
        float var = Q * (1.f / Oo) - mu * mu;
        musig[t][0] = mu;
        musig[t][1] = rsqrtf(var + EPSc);
    }
    __syncthreads();

    float mn0 = musig[colA][0],      rs0 = musig[colA][1];
    float mn1 = musig[16 + colA][0], rs1 = musig[16 + colA][1];
    #pragma unroll
    for (int ot = 0; ot < 4; ++ot) {
        #pragma unroll
        for (int r = 0; r < 4; ++r) {
            int o = wave * 64 + ot * 16 + kgrp * 4 + r;
            float gg = g2[o], bb2 = b2[o];
            size_t ob = ((size_t)b * Oo + o) * Nn + n0;
            out[ob + colA]      = (acc[ot][0][r] - mn0) * rs0 * gg + bb2;
            out[ob + 16 + colA] = (acc[ot][1][r] - mn1) * rs1 * gg + bb2;
        }
    }
}

extern "C" void kernel_launch(void* const* d_in, const int* in_sizes, int n_in,
                              void* d_out, int out_size, void* d_ws, size_t ws_size,
                              hipStream_t stream)
{
    (void)in_sizes; (void)n_in; (void)out_size;
    const float* x1 = (const float*)d_in[0];
    const float* x2 = (const float*)d_in[1];
    const float* g1 = (const float*)d_in[2];
    const float* b1 = (const float*)d_in[3];
    const float* Wr = (const float*)d_in[4];
    const float* br = (const float*)d_in[5];
    const float* g2 = (const float*)d_in[6];
    const float* b2 = (const float*)d_in[7];
    const float* a1 = (const float*)d_in[8];
    const float* a2 = (const float*)d_in[9];
    const float* a3 = (const float*)d_in[10];
    const float* a4 = (const float*)d_in[11];
    float* ws = (float*)d_ws;
    float* out = (float*)d_out;

    // adaptive split-K: nks must divide 144 (so krange % 64 == 0) and partials must fit ws
    const int cand[6] = {24, 16, 12, 8, 4, 2};
    int nks = 2;
    for (int ci = 0; ci < 6; ++ci) {
        if (((size_t)OFF_CTXP + (size_t)cand[ci] * 524288ull) * 4ull <= ws_size) { nks = cand[ci]; break; }
    }

    hipLaunchKernelGGL(mg_k0_zero, dim3(2), dim3(256), 0, stream, ws + OFF_COLSUM, 512);
    hipLaunchKernelGGL(mg_k1_stats, dim3(1152), dim3(256), 0, stream, x1, x2, g1, b1, ws);
    hipLaunchKernelGGL(mg_k3_ctx, dim3(Bc * nks), dim3(512), 0, stream, x1, x2, g1, b1, ws, nks);
    hipLaunchKernelGGL(mg_k5_mask, dim3(2048), dim3(256), 0, stream, a1, a2, a3, a4, ws, nks);
    hipLaunchKernelGGL(mg_k6_w2, dim3(256), dim3(256), 0, stream, Wr, ws);
    hipLaunchKernelGGL(mg_k7_final, dim3(2304), dim3(512), 0, stream, x2, g1, b1, br, g2, b2, ws, out);
}

// Round 17
// 191.149 us; speedup vs baseline: 1.2773x; 1.0196x over previous
//
#include <hip/hip_runtime.h>
#include <hip/hip_bf16.h>

#define Bc 8
#define Nn 9216
#define Dd 256
#define Oo 512
#define EPSc 1e-5f

// workspace float offsets
#define OFF_MU1    0          // 73728
#define OFF_RSTD1  73728
#define OFF_MU2    147456
#define OFF_RSTD2  221184
#define OFF_ROWINV 294912
#define OFF_COLSUM 368640     // 2048
#define OFF_M      370688     // 524288
#define OFF_W2T    894976     // W2 bf16 frag-linear: 1,048,576 ushorts
#define OFF_CTXP   1419264    // nks * 524288 floats of ctx partials (adaptive)

typedef __attribute__((ext_vector_type(4))) float f32x4;
typedef __attribute__((ext_vector_type(8))) short short8;
typedef __attribute__((ext_vector_type(8))) unsigned short ushort8;

static __device__ __forceinline__ unsigned short f2bf(float f) {
    __hip_bfloat16 h = __float2bfloat16(f);
    union { __hip_bfloat16 hh; unsigned short uu; } cv; cv.hh = h;
    return cv.uu;
}

// granule swizzle for channel-major bf16 tiles [ch][64n]: write conflict-free, read ~2-way
#define SWZ(ch) (((((ch) >> 2) & 7)) ^ ((((ch) & 3)) << 1))

__global__ __launch_bounds__(256) void mg_k0_zero(float* __restrict__ p, int n4) {
    int i = blockIdx.x * 256 + threadIdx.x;
    if (i < n4) ((float4*)p)[i] = make_float4(0.f, 0.f, 0.f, 0.f);
}

// K1: one pass over x1,x2. Per row: LN stats for both; query row-sumexp; col-sumexp partials -> atomics.
__global__ __launch_bounds__(256) void mg_k1_stats(const float* __restrict__ x1, const float* __restrict__ x2,
                                                   const float* __restrict__ g1, const float* __restrict__ b1,
                                                   float* __restrict__ ws)
{
    float* mu1    = ws + OFF_MU1;
    float* rstd1  = ws + OFF_RSTD1;
    float* mu2    = ws + OFF_MU2;
    float* rstd2  = ws + OFF_RSTD2;
    float* rowinv = ws + OFF_ROWINV;
    float* colsum = ws + OFF_COLSUM;

    int t = threadIdx.x, lane = t & 63, w = t >> 6;
    int b = blockIdx.x / 144, rb = blockIdx.x % 144;
    int nbase = rb * 64;

    float4 g1v = ((const float4*)g1)[lane];
    float4 b1v = ((const float4*)b1)[lane];
    float cs0 = 0.f, cs1 = 0.f, cs2 = 0.f, cs3 = 0.f;
    __shared__ float csL[4][256];

    for (int i = 0; i < 16; ++i) {
        int n = nbase + i * 4 + w;
        int base = (b * Nn + n) * 64 + lane;
        float4 xa = ((const float4*)x1)[base];
        float4 xb = ((const float4*)x2)[base];
        float s1 = xa.x + xa.y + xa.z + xa.w;
        float q1 = xa.x*xa.x + xa.y*xa.y + xa.z*xa.z + xa.w*xa.w;
        float s2 = xb.x + xb.y + xb.z + xb.w;
        float q2 = xb.x*xb.x + xb.y*xb.y + xb.z*xb.z + xb.w*xb.w;
        #pragma unroll
        for (int m = 1; m < 64; m <<= 1) {
            s1 += __shfl_xor(s1, m); q1 += __shfl_xor(q1, m);
            s2 += __shfl_xor(s2, m); q2 += __shfl_xor(q2, m);
        }
        float m1 = s1 * (1.f / Dd), m2 = s2 * (1.f / Dd);
        float r1 = rsqrtf(q1 * (1.f / Dd) - m1 * m1 + EPSc);
        float r2 = rsqrtf(q2 * (1.f / Dd) - m2 * m2 + EPSc);
        int ni = b * Nn + n;
        if (lane == 0) { mu1[ni] = m1; rstd1[ni] = r1; mu2[ni] = m2; rstd2[ni] = r2; }
        // LN(x2) values are bounded -> exp without max-subtraction is safe in f32
        float e0 = __expf((xb.x - m2) * r2 * g1v.x + b1v.x);
        float e1 = __expf((xb.y - m2) * r2 * g1v.y + b1v.y);
        float e2 = __expf((xb.z - m2) * r2 * g1v.z + b1v.z);
        float e3 = __expf((xb.w - m2) * r2 * g1v.w + b1v.w);
        float rs = e0 + e1 + e2 + e3;
        #pragma unroll
        for (int m = 1; m < 64; m <<= 1) rs += __shfl_xor(rs, m);
        if (lane == 0) rowinv[ni] = 1.f / rs;
        cs0 += e0; cs1 += e1; cs2 += e2; cs3 += e3;
    }
    csL[w][lane * 4 + 0] = cs0;
    csL[w][lane * 4 + 1] = cs1;
    csL[w][lane * 4 + 2] = cs2;
    csL[w][lane * 4 + 3] = cs3;
    __syncthreads();
    float tot = csL[0][t] + csL[1][t] + csL[2][t] + csL[3][t];
    atomicAdd(&colsum[b * Dd + t], tot);
}

// K3 (MFMA): ctx_partial[p][b][d][e] = sum_{n in slice p} exp(n2[n][d]) * n1[n][e]
// grid: b(8) x ks(nks); block 512 thr (8 waves), tile 256d x 256e, K-tile 64 n.
__global__ __launch_bounds__(512, 2) void mg_k3_ctx(const float* __restrict__ x1, const float* __restrict__ x2,
                                                    const float* __restrict__ g1, const float* __restrict__ b1,
                                                    float* __restrict__ ws, int nks)
{
    __shared__ ushort PA[256 * 64];   // exp(n2): [d][n]
    __shared__ ushort PB[256 * 64];   // n1:      [e][n]
    const float* mu1   = ws + OFF_MU1;
    const float* rstd1 = ws + OFF_RSTD1;
    const float* mu2   = ws + OFF_MU2;
    const float* rstd2 = ws + OFF_RSTD2;
    float* ctxp = ws + OFF_CTXP;

    int t = threadIdx.x;
    int ks_i = blockIdx.x % nks;
    int b = blockIdx.x / nks;
    int krange = Nn / nks;
    int ntiles = krange >> 6;
    int n_base = ks_i * krange;

    int o  = t >> 6;
    int c4 = t & 63;

    f32x4 g1v = ((const f32x4*)g1)[c4];
    f32x4 b1v = ((const f32x4*)b1)[c4];

    int lane = t & 63, wave = t >> 6;
    int wd = wave & 3, we = wave >> 2;
    int l15 = lane & 15, kgrp = lane >> 4;

    f32x4 acc[4][8];
    #pragma unroll
    for (int dt = 0; dt < 4; ++dt)
        #pragma unroll
        for (int et = 0; et < 8; ++et) acc[dt][et] = (f32x4){0.f, 0.f, 0.f, 0.f};

    for (int st = 0; st < ntiles; ++st) {
        int rowb = b * Nn + n_base + st * 64 + o * 8;
        __syncthreads();
        {
            f32x4 mv0 = *(const f32x4*)(mu1 + rowb),   mv1 = *(const f32x4*)(mu1 + rowb + 4);
            f32x4 rv0 = *(const f32x4*)(rstd1 + rowb), rv1 = *(const f32x4*)(rstd1 + rowb + 4);
            float mva[8] = {mv0[0], mv0[1], mv0[2], mv0[3], mv1[0], mv1[1], mv1[2], mv1[3]};
            float rva[8] = {rv0[0], rv0[1], rv0[2], rv0[3], rv1[0], rv1[1], rv1[2], rv1[3]};
            f32x4 xv[8];
            #pragma unroll
            for (int rr = 0; rr < 8; ++rr)
                xv[rr] = ((const f32x4*)x1)[(size_t)(rowb + rr) * 64 + c4];
            #pragma unroll
            for (int i = 0; i < 4; ++i) {
                int ch = c4 * 4 + i;
                ushort8 u;
                #pragma unroll
                for (int rr = 0; rr < 8; ++rr)
                    u[rr] = f2bf((xv[rr][i] - mva[rr]) * rva[rr] * g1v[i] + b1v[i]);
                *(ushort8*)&PB[ch * 64 + ((o + SWZ(ch)) & 7) * 8] = u;
            }
        }
        {
            f32x4 mv0 = *(const f32x4*)(mu2 + rowb),   mv1 = *(const f32x4*)(mu2 + rowb + 4);
            f32x4 rv0 = *(const f32x4*)(rstd2 + rowb), rv1 = *(const f32x4*)(rstd2 + rowb + 4);
            float mva[8] = {mv0[0], mv0[1], mv0[2], mv0[3], mv1[0], mv1[1], mv1[2], mv1[3]};
            float rva[8] = {rv0[0], rv0[1], rv0[2], rv0[3], rv1[0], rv1[1], rv1[2], rv1[3]};
            f32x4 xv[8];
            #pragma unroll
            for (int rr = 0; rr < 8; ++rr)
                xv[rr] = ((const f32x4*)x2)[(size_t)(rowb + rr) * 64 + c4];
            #pragma unroll
            for (int i = 0; i < 4; ++i) {
                int ch = c4 * 4 + i;
                ushort8 u;
                #pragma unroll
                for (int rr = 0; rr < 8; ++rr)
                    u[rr] = f2bf(__expf((xv[rr][i] - mva[rr]) * rva[rr] * g1v[i] + b1v[i]));
                *(ushort8*)&PA[ch * 64 + ((o + SWZ(ch)) & 7) * 8] = u;
            }
        }
        __syncthreads();

        #pragma unroll
        for (int kk = 0; kk < 2; ++kk) {
            short8 af[4], bf[8];
            #pragma unroll
            for (int dt = 0; dt < 4; ++dt) {
                int ch = wd * 64 + dt * 16 + l15;
                af[dt] = *(const short8*)&PA[ch * 64 + (((kk << 2) + kgrp + SWZ(ch)) & 7) * 8];
            }
            #pragma unroll
            for (int et = 0; et < 8; ++et) {
                int ch = we * 128 + et * 16 + l15;
                bf[et] = *(const short8*)&PB[ch * 64 + (((kk << 2) + kgrp + SWZ(ch)) & 7) * 8];
            }
            #pragma unroll
            for (int dt = 0; dt < 4; ++dt)
                #pragma unroll
                for (int et = 0; et < 8; ++et)
                    acc[dt][et] = __builtin_amdgcn_mfma_f32_16x16x32_bf16(af[dt], bf[et], acc[dt][et], 0, 0, 0);
        }
    }

    size_t obase = ((size_t)ks_i * Bc + b) * (Dd * Dd);
    #pragma unroll
    for (int dt = 0; dt < 4; ++dt) {
        #pragma unroll
        for (int r = 0; r < 4; ++r) {
            int d = wd * 64 + dt * 16 + kgrp * 4 + r;
            float* rowp = ctxp + obase + (size_t)d * Dd + we * 128 + l15;
            #pragma unroll
            for (int et = 0; et < 8; ++et)
                rowp[et * 16] = acc[dt][et][r];
        }
    }
}

// K5: reduce ctx partials, scale by 1/colsum, bitonic sort (desc), 4 top-k thresholds,
// combined masked softmax M = sum_i a_i * softmax_masked_i.  grid = B*D rows.
__global__ __launch_bounds__(256) void mg_k5_mask(const float* __restrict__ a1p, const float* __restrict__ a2p,
                                                  const float* __restrict__ a3p, const float* __restrict__ a4p,
                                                  float* __restrict__ ws, int nks)
{
    const float* ctxp   = ws + OFF_CTXP;
    const float* colsum = ws + OFF_COLSUM;
    float* Mo = ws + OFF_M;
    int t = threadIdx.x;
    int b = blockIdx.x >> 8, d = blockIdx.x & 255;
    __shared__ float s[256];
    __shared__ float wred[4][4];

    float c = 0.f;
    for (int p = 0; p < nks; ++p)
        c += ctxp[((size_t)p * Bc + b) * (Dd * Dd) + (size_t)d * Dd + t];
    float inv = 1.f / colsum[b * Dd + d];
    c *= inv;
    s[t] = c;
    __syncthreads();
    for (int k = 2; k <= 256; k <<= 1) {
        for (int j = k >> 1; j > 0; j >>= 1) {
            int ixj = t ^ j;
            if (ixj > t) {
                float A = s[t], Bv = s[ixj];
                bool desc = ((t & k) == 0);
                bool sw = desc ? (A < Bv) : (A > Bv);
                if (sw) { s[t] = Bv; s[ixj] = A; }
            }
            __syncthreads();
        }
    }
    float cmax = s[0];
    float t0 = s[127], t1 = s[169], t2 = s[191], t3 = s[203];  // k-1 for k = 128,170,192,204
    float e = __expf(c - cmax);
    float w0 = (c >= t0) ? e : 0.f;
    float w1 = (c >= t1) ? e : 0.f;
    float w2 = (c >= t2) ? e : 0.f;
    float w3 = (c >= t3) ? e : 0.f;
    float v0 = w0, v1 = w1, v2 = w2, v3 = w3;
    #pragma unroll
    for (int m = 1; m < 64; m <<= 1) {
        v0 += __shfl_xor(v0, m); v1 += __shfl_xor(v1, m);
        v2 += __shfl_xor(v2, m); v3 += __shfl_xor(v3, m);
    }
    int lane = t & 63, wv = t >> 6;
    if (lane == 0) { wred[wv][0] = v0; wred[wv][1] = v1; wred[wv][2] = v2; wred[wv][3] = v3; }
    __syncthreads();
    float S0 = wred[0][0] + wred[1][0] + wred[2][0] + wred[3][0];
    float S1 = wred[0][1] + wred[1][1] + wred[2][1] + wred[3][1];
    float S2 = wred[0][2] + wred[1][2] + wred[2][2] + wred[3][2];
    float S3 = wred[0][3] + wred[1][3] + wred[2][3] + wred[3][3];
    float Mv = a1p[0] * (w0 / S0) + a2p[0] * (w1 / S1) + a3p[0] * (w2 / S2) + a4p[0] * (w3 / S3);
    Mo[(b * Dd + d) * Dd + t] = Mv;
}

// K6: W2 bf16 in FRAG-LINEAR layout for K7's LDS staging:
// ushort idx = ((b*8+ks)*16384) + wave*2048 + ot*512 + (kgrp*16+colA)*8 + j
// where o = wave*64+ot*16+colA, e = ks*32+kgrp*8+j.
__global__ __launch_bounds__(256) void mg_k6_w2(const float* __restrict__ Wr, float* __restrict__ ws)
{
    const float* Mo = ws + OFF_M;
    ushort* W2B = (ushort*)(ws + OFF_W2T);
    __shared__ float Mt[32][128];
    __shared__ float WrT[32][36];
    int t = threadIdx.x;
    int b = blockIdx.x >> 5, ob = (blockIdx.x >> 1) & 15, eh = blockIdx.x & 1;
    int o0 = ob * 32, e0 = eh * 128;
    int ol4 = t & 7, el = t >> 3;
    float acc[4][4];
    #pragma unroll
    for (int i = 0; i < 4; ++i)
        #pragma unroll
        for (int j = 0; j < 4; ++j) acc[i][j] = 0.f;

    for (int ch = 0; ch < 8; ++ch) {
        int c0 = ch * 32;
        __syncthreads();
        #pragma unroll
        for (int k = 0; k < 4; ++k) {
            int fi = t + k * 256;
            int row = fi >> 5, c4 = fi & 31;
            float4 mv = ((const float4*)Mo)[(b * Dd + c0 + row) * 64 + (e0 >> 2) + c4];
            *(float4*)&Mt[row][c4 * 4] = mv;
        }
        {
            int ol = t >> 3, c4 = t & 7;
            float4 wv = ((const float4*)Wr)[(o0 + ol) * 64 + (c0 >> 2) + c4];
            WrT[c4 * 4 + 0][ol] = wv.x;
            WrT[c4 * 4 + 1][ol] = wv.y;
            WrT[c4 * 4 + 2][ol] = wv.z;
            WrT[c4 * 4 + 3][ol] = wv.w;
        }
        __syncthreads();
        #pragma unroll
        for (int cc = 0; cc < 32; ++cc) {
            float4 w4 = *(const float4*)&WrT[cc][ol4 * 4];
            float4 m4 = *(const float4*)&Mt[cc][el * 4];
            float wv[4] = {w4.x, w4.y, w4.z, w4.w};
            float mv[4] = {m4.x, m4.y, m4.z, m4.w};
            #pragma unroll
            for (int i = 0; i < 4; ++i)
                #pragma unroll
                for (int j = 0; j < 4; ++j)
                    acc[i][j] = fmaf(wv[i], mv[j], acc[i][j]);
        }
    }
    {
        int e_base = e0 + el * 4;
        int ks = e_base >> 5;
        int kg = (e_base >> 3) & 3, jj = e_base & 7;   // jj in {0,4}
        #pragma unroll
        for (int i = 0; i < 4; ++i) {
            int o = o0 + ol4 * 4 + i;
            int wv2 = o >> 6, ot = (o >> 4) & 3, cA = o & 15;
            ushort4 u;
            u.x = f2bf(acc[i][0]); u.y = f2bf(acc[i][1]);
            u.z = f2bf(acc[i][2]); u.w = f2bf(acc[i][3]);
            size_t idx = ((size_t)b * 8 + ks) * 16384 + wv2 * 2048 + ot * 512
                       + (kg * 16 + cA) * 8 + jj;
            *(ushort4*)&W2B[idx] = u;
        }
    }
}

// K7 v8 (gload_lds 2-phase, proven R13): W2 staged per K-step via global_load_lds into
// double-buffered LDS (frag-linear); stage(ks+1) issued BEFORE MFMA(ks) so loads fly
// under compute; one barrier per K-step drains.
__global__ __launch_bounds__(512) void mg_k7_final(const float* __restrict__ x2,
        const float* __restrict__ g1, const float* __restrict__ b1,
        const float* __restrict__ br, const float* __restrict__ g2, const float* __restrict__ b2,
        const float* __restrict__ ws, float* __restrict__ out)
{
    __shared__ ushort smem[8192 + 2 * 16384];   // qsT 16KB + W2 dbuf 64KB = 80KB
    ushort* qsT = smem;
    ushort* W0 = smem + 8192;
    ushort* W1 = smem + 8192 + 16384;

    const float* mu2    = ws + OFF_MU2;
    const float* rstd2  = ws + OFF_RSTD2;
    const float* rowinv = ws + OFF_ROWINV;
    const ushort* W2B   = (const ushort*)(ws + OFF_W2T);

    int t = threadIdx.x;
    int b = blockIdx.x / 288, nt0 = blockIdx.x % 288;
    int n0 = nt0 * 32;
    int lw = t & 63, wave = t >> 6;
    int colA = lw & 15, kgrp = lw >> 4;

#define STAGEW(dstbuf, ksv)                                                        \
    {                                                                              \
        size_t so_ = ((size_t)b * 8 + (ksv)) * 16384 + wave * 2048;                \
        _Pragma("unroll")                                                          \
        for (int k_ = 0; k_ < 4; ++k_) {                                           \
            __builtin_amdgcn_global_load_lds(                                      \
                (const __attribute__((address_space(1))) unsigned int*)            \
                    (W2B + so_ + k_ * 512 + lw * 8),                               \
                (__attribute__((address_space(3))) unsigned int*)                  \
                    ((dstbuf) + wave * 2048 + k_ * 512),                           \
                16, 0, 0);                                                         \
        }                                                                          \
    }

    STAGEW(W0, 0);

    {
        int row = t >> 4, gpair = (t & 15) * 2;
        int ni = b * Nn + n0 + row;
        float m = mu2[ni], r = rstd2[ni], ri = rowinv[ni];
        #pragma unroll
        for (int jj = 0; jj < 2; ++jj) {
            int g = gpair + jj;
            const float4* xp = (const float4*)x2 + (size_t)ni * 64 + g * 2;
            float4 xa = xp[0], xb = xp[1];
            float4 ga = ((const float4*)g1)[g * 2], gc = ((const float4*)g1)[g * 2 + 1];
            float4 ba = ((const float4*)b1)[g * 2], bc = ((const float4*)b1)[g * 2 + 1];
            float v[8]  = {xa.x, xa.y, xa.z, xa.w, xb.x, xb.y, xb.z, xb.w};
            float gv[8] = {ga.x, ga.y, ga.z, ga.w, gc.x, gc.y, gc.z, gc.w};
            float bv[8] = {ba.x, ba.y, ba.z, ba.w, bc.x, bc.y, bc.z, bc.w};
            ushort8 u;
            #pragma unroll
            for (int q = 0; q < 8; ++q)
                u[q] = f2bf(__expf((v[q] - m) * r * gv[q] + bv[q]) * ri);
            *(ushort8*)&qsT[row * 256 + ((g ^ (row & 7)) << 3)] = u;
        }
    }
    __syncthreads();

    f32x4 acc[4][2];
    #pragma unroll
    for (int ot = 0; ot < 4; ++ot) {
        acc[ot][0] = (f32x4){0.f, 0.f, 0.f, 0.f};
        acc[ot][1] = (f32x4){0.f, 0.f, 0.f, 0.f};
    }

    #pragma unroll
    for (int ks = 0; ks < 8; ++ks) {
        if (ks < 7) {
            if ((ks & 1) == 0) { STAGEW(W1, ks + 1); }
            else               { STAGEW(W0, ks + 1); }
        }
        const ushort* wb = (ks & 1) ? W1 : W0;
        int gsl = ((ks * 4 + kgrp) ^ (colA & 7)) << 3;
        short8 bf0 = *(const short8*)&qsT[colA * 256 + gsl];
        short8 bf1 = *(const short8*)&qsT[(16 + colA) * 256 + gsl];
        #pragma unroll
        for (int ot = 0; ot < 4; ++ot) {
            short8 af = *(const short8*)&wb[wave * 2048 + ot * 512 + lw * 8];
            acc[ot][0] = __builtin_amdgcn_mfma_f32_16x16x32_bf16(af, bf0, acc[ot][0], 0, 0, 0);
            acc[ot][1] = __builtin_amdgcn_mfma_f32_16x16x32_bf16(af, bf1, acc[ot][1], 0, 0, 0);
        }
        __syncthreads();
    }
#undef STAGEW

    float (*stat)[2][16][2] = (float (*)[2][16][2])(void*)smem;
    float (*musig)[2] = (float (*)[2])((float*)(void*)smem + 512);

    float ps[2] = {0.f, 0.f}, pq[2] = {0.f, 0.f};
    #pragma unroll
    for (int ot = 0; ot < 4; ++ot) {
        #pragma unroll
        for (int r = 0; r < 4; ++r) {
            int o = wave * 64 + ot * 16 + kgrp * 4 + r;
            float bb = br[o];
            float v0 = acc[ot][0][r] + bb;
            float v1 = acc[ot][1][r] + bb;
            acc[ot][0][r] = v0; acc[ot][1][r] = v1;
            ps[0] += v0; pq[0] += v0 * v0;
            ps[1] += v1; pq[1] += v1 * v1;
        }
    }
    #pragma unroll
    for (int m = 16; m <= 32; m <<= 1) {
        ps[0] += __shfl_xor(ps[0], m); pq[0] += __shfl_xor(pq[0], m);
        ps[1] += __shfl_xor(ps[1], m); pq[1] += __shfl_xor(pq[1], m);
    }
    if (lw < 16) {
        stat[wave][0][lw][0] = ps[0]; stat[wave][0][lw][1] = pq[0];
        stat[wave][1][lw][0] = ps[1]; stat[wave][1][lw][1] = pq[1];
    }
    __syncthreads();
    if (t < 32) {
        int ntl = t >> 4, col = t & 15;
        float S = 0.f, Q = 0.f;
        #pragma unroll
        for (int w2 = 0; w2 < 8; ++w2) { S += stat[w2][ntl][col][0]; Q += stat[w2][ntl][col][1]; }
        float mu = S * (1.f / Oo);
        float var = Q * (1.f / Oo) - mu * mu;
        musig[t][0] = mu;
        musig[t][1] = rsqrtf(var + EPSc);
    }
    __syncthreads();

    float mn0 = musig[colA][0],      rs0 = musig[colA][1];
    float mn1 = musig[16 + colA][0], rs1 = musig[16 + colA][1];
    #pragma unroll
    for (int ot = 0; ot < 4; ++ot) {
        #pragma unroll
        for (int r = 0; r < 4; ++r) {
            int o = wave * 64 + ot * 16 + kgrp * 4 + r;
            float gg = g2[o], bb2 = b2[o];
            size_t ob = ((size_t)b * Oo + o) * Nn + n0;
            out[ob + colA]      = (acc[ot][0][r] - mn0) * rs0 * gg + bb2;
            out[ob + 16 + colA] = (acc[ot][1][r] - mn1) * rs1 * gg + bb2;
        }
    }
}

extern "C" void kernel_launch(void* const* d_in, const int* in_sizes, int n_in,
                              void* d_out, int out_size, void* d_ws, size_t ws_size,
                              hipStream_t stream)
{
    (void)in_sizes; (void)n_in; (void)out_size;
    const float* x1 = (const float*)d_in[0];
    const float* x2 = (const float*)d_in[1];
    const float* g1 = (const float*)d_in[2];
    const float* b1 = (const float*)d_in[3];
    const float* Wr = (const float*)d_in[4];
    const float* br = (const float*)d_in[5];
    const float* g2 = (const float*)d_in[6];
    const float* b2 = (const float*)d_in[7];
    const float* a1 = (const float*)d_in[8];
    const float* a2 = (const float*)d_in[9];
    const float* a3 = (const float*)d_in[10];
    const float* a4 = (const float*)d_in[11];
    float* ws = (float*)d_ws;
    float* out = (float*)d_out;

    // adaptive split-K: nks must divide 144 (so krange % 64 == 0) and partials must fit ws
    const int cand[6] = {24, 16, 12, 8, 4, 2};
    int nks = 2;
    for (int ci = 0; ci < 6; ++ci) {
        if (((size_t)OFF_CTXP + (size_t)cand[ci] * 524288ull) * 4ull <= ws_size) { nks = cand[ci]; break; }
    }

    hipLaunchKernelGGL(mg_k0_zero, dim3(2), dim3(256), 0, stream, ws + OFF_COLSUM, 512);
    hipLaunchKernelGGL(mg_k1_stats, dim3(1152), dim3(256), 0, stream, x1, x2, g1, b1, ws);
    hipLaunchKernelGGL(mg_k3_ctx, dim3(Bc * nks), dim3(512), 0, stream, x1, x2, g1, b1, ws, nks);
    hipLaunchKernelGGL(mg_k5_mask, dim3(2048), dim3(256), 0, stream, a1, a2, a3, a4, ws, nks);
    hipLaunchKernelGGL(mg_k6_w2, dim3(256), dim3(256), 0, stream, Wr, ws);
    hipLaunchKernelGGL(mg_k7_final, dim3(2304), dim3(512), 0, stream, x2, g1, b1, br, g2, b2, ws, out);
}

// Round 18
// 186.628 us; speedup vs baseline: 1.3082x; 1.0242x over previous
//
#include <hip/hip_runtime.h>
#include <hip/hip_bf16.h>

#define Bc 8
#define Nn 9216
#define Dd 256
#define Oo 512
#define EPSc 1e-5f

// workspace float offsets
#define OFF_MU1    0          // 73728
#define OFF_RSTD1  73728
#define OFF_MU2    147456
#define OFF_RSTD2  221184
#define OFF_ROWINV 294912
#define OFF_COLSUM 368640     // 2048
#define OFF_M      370688     // 524288
#define OFF_W2T    894976     // W2 bf16 frag-linear: 1,048,576 ushorts
#define OFF_CTXP   1419264    // nks * 524288 floats of ctx partials (adaptive)

typedef __attribute__((ext_vector_type(4))) float f32x4;
typedef __attribute__((ext_vector_type(8))) short short8;
typedef __attribute__((ext_vector_type(8))) unsigned short ushort8;

static __device__ __forceinline__ unsigned short f2bf(float f) {
    __hip_bfloat16 h = __float2bfloat16(f);
    union { __hip_bfloat16 hh; unsigned short uu; } cv; cv.hh = h;
    return cv.uu;
}

// granule swizzle for channel-major bf16 tiles [ch][64n]: write conflict-free, read ~2-way
#define SWZ(ch) (((((ch) >> 2) & 7)) ^ ((((ch) & 3)) << 1))

__global__ __launch_bounds__(256) void mg_k0_zero(float* __restrict__ p, int n4) {
    int i = blockIdx.x * 256 + threadIdx.x;
    if (i < n4) ((float4*)p)[i] = make_float4(0.f, 0.f, 0.f, 0.f);
}

// K1: one pass over x1,x2. Per row: LN stats for both; query row-sumexp; col-sumexp partials -> atomics.
__global__ __launch_bounds__(256) void mg_k1_stats(const float* __restrict__ x1, const float* __restrict__ x2,
                                                   const float* __restrict__ g1, const float* __restrict__ b1,
                                                   float* __restrict__ ws)
{
    float* mu1    = ws + OFF_MU1;
    float* rstd1  = ws + OFF_RSTD1;
    float* mu2    = ws + OFF_MU2;
    float* rstd2  = ws + OFF_RSTD2;
    float* rowinv = ws + OFF_ROWINV;
    float* colsum = ws + OFF_COLSUM;

    int t = threadIdx.x, lane = t & 63, w = t >> 6;
    int b = blockIdx.x / 144, rb = blockIdx.x % 144;
    int nbase = rb * 64;

    float4 g1v = ((const float4*)g1)[lane];
    float4 b1v = ((const float4*)b1)[lane];
    float cs0 = 0.f, cs1 = 0.f, cs2 = 0.f, cs3 = 0.f;
    __shared__ float csL[4][256];

    for (int i = 0; i < 16; ++i) {
        int n = nbase + i * 4 + w;
        int base = (b * Nn + n) * 64 + lane;
        float4 xa = ((const float4*)x1)[base];
        float4 xb = ((const float4*)x2)[base];
        float s1 = xa.x + xa.y + xa.z + xa.w;
        float q1 = xa.x*xa.x + xa.y*xa.y + xa.z*xa.z + xa.w*xa.w;
        float s2 = xb.x + xb.y + xb.z + xb.w;
        float q2 = xb.x*xb.x + xb.y*xb.y + xb.z*xb.z + xb.w*xb.w;
        #pragma unroll
        for (int m = 1; m < 64; m <<= 1) {
            s1 += __shfl_xor(s1, m); q1 += __shfl_xor(q1, m);
            s2 += __shfl_xor(s2, m); q2 += __shfl_xor(q2, m);
        }
        float m1 = s1 * (1.f / Dd), m2 = s2 * (1.f / Dd);
        float r1 = rsqrtf(q1 * (1.f / Dd) - m1 * m1 + EPSc);
        float r2 = rsqrtf(q2 * (1.f / Dd) - m2 * m2 + EPSc);
        int ni = b * Nn + n;
        if (lane == 0) { mu1[ni] = m1; rstd1[ni] = r1; mu2[ni] = m2; rstd2[ni] = r2; }
        // LN(x2) values are bounded -> exp without max-subtraction is safe in f32
        float e0 = __expf((xb.x - m2) * r2 * g1v.x + b1v.x);
        float e1 = __expf((xb.y - m2) * r2 * g1v.y + b1v.y);
        float e2 = __expf((xb.z - m2) * r2 * g1v.z + b1v.z);
        float e3 = __expf((xb.w - m2) * r2 * g1v.w + b1v.w);
        float rs = e0 + e1 + e2 + e3;
        #pragma unroll
        for (int m = 1; m < 64; m <<= 1) rs += __shfl_xor(rs, m);
        if (lane == 0) rowinv[ni] = 1.f / rs;
        cs0 += e0; cs1 += e1; cs2 += e2; cs3 += e3;
    }
    csL[w][lane * 4 + 0] = cs0;
    csL[w][lane * 4 + 1] = cs1;
    csL[w][lane * 4 + 2] = cs2;
    csL[w][lane * 4 + 3] = cs3;
    __syncthreads();
    float tot = csL[0][t] + csL[1][t] + csL[2][t] + csL[3][t];
    atomicAdd(&colsum[b * Dd + t], tot);
}

// K3 (MFMA): ctx_partial[p][b][d][e] = sum_{n in slice p} exp(n2[n][d]) * n1[n][e]
// grid: b(8) x ks(nks); block 512 thr (8 waves), tile 256d x 256e, K-tile 64 n.
__global__ __launch_bounds__(512, 2) void mg_k3_ctx(const float* __restrict__ x1, const float* __restrict__ x2,
                                                    const float* __restrict__ g1, const float* __restrict__ b1,
                                                    float* __restrict__ ws, int nks)
{
    __shared__ ushort PA[256 * 64];   // exp(n2): [d][n]
    __shared__ ushort PB[256 * 64];   // n1:      [e][n]
    const float* mu1   = ws + OFF_MU1;
    const float* rstd1 = ws + OFF_RSTD1;
    const float* mu2   = ws + OFF_MU2;
    const float* rstd2 = ws + OFF_RSTD2;
    float* ctxp = ws + OFF_CTXP;

    int t = threadIdx.x;
    int ks_i = blockIdx.x % nks;
    int b = blockIdx.x / nks;
    int krange = Nn / nks;
    int ntiles = krange >> 6;
    int n_base = ks_i * krange;

    int o  = t >> 6;
    int c4 = t & 63;

    f32x4 g1v = ((const f32x4*)g1)[c4];
    f32x4 b1v = ((const f32x4*)b1)[c4];

    int lane = t & 63, wave = t >> 6;
    int wd = wave & 3, we = wave >> 2;
    int l15 = lane & 15, kgrp = lane >> 4;

    f32x4 acc[4][8];
    #pragma unroll
    for (int dt = 0; dt < 4; ++dt)
        #pragma unroll
        for (int et = 0; et < 8; ++et) acc[dt][et] = (f32x4){0.f, 0.f, 0.f, 0.f};

    for (int st = 0; st < ntiles; ++st) {
        int rowb = b * Nn + n_base + st * 64 + o * 8;
        __syncthreads();
        {
            f32x4 mv0 = *(const f32x4*)(mu1 + rowb),   mv1 = *(const f32x4*)(mu1 + rowb + 4);
            f32x4 rv0 = *(const f32x4*)(rstd1 + rowb), rv1 = *(const f32x4*)(rstd1 + rowb + 4);
            float mva[8] = {mv0[0], mv0[1], mv0[2], mv0[3], mv1[0], mv1[1], mv1[2], mv1[3]};
            float rva[8] = {rv0[0], rv0[1], rv0[2], rv0[3], rv1[0], rv1[1], rv1[2], rv1[3]};
            f32x4 xv[8];
            #pragma unroll
            for (int rr = 0; rr < 8; ++rr)
                xv[rr] = ((const f32x4*)x1)[(size_t)(rowb + rr) * 64 + c4];
            #pragma unroll
            for (int i = 0; i < 4; ++i) {
                int ch = c4 * 4 + i;
                ushort8 u;
                #pragma unroll
                for (int rr = 0; rr < 8; ++rr)
                    u[rr] = f2bf((xv[rr][i] - mva[rr]) * rva[rr] * g1v[i] + b1v[i]);
                *(ushort8*)&PB[ch * 64 + ((o + SWZ(ch)) & 7) * 8] = u;
            }
        }
        {
            f32x4 mv0 = *(const f32x4*)(mu2 + rowb),   mv1 = *(const f32x4*)(mu2 + rowb + 4);
            f32x4 rv0 = *(const f32x4*)(rstd2 + rowb), rv1 = *(const f32x4*)(rstd2 + rowb + 4);
            float mva[8] = {mv0[0], mv0[1], mv0[2], mv0[3], mv1[0], mv1[1], mv1[2], mv1[3]};
            float rva[8] = {rv0[0], rv0[1], rv0[2], rv0[3], rv1[0], rv1[1], rv1[2], rv1[3]};
            f32x4 xv[8];
            #pragma unroll
            for (int rr = 0; rr < 8; ++rr)
                xv[rr] = ((const f32x4*)x2)[(size_t)(rowb + rr) * 64 + c4];
            #pragma unroll
            for (int i = 0; i < 4; ++i) {
                int ch = c4 * 4 + i;
                ushort8 u;
                #pragma unroll
                for (int rr = 0; rr < 8; ++rr)
                    u[rr] = f2bf(__expf((xv[rr][i] - mva[rr]) * rva[rr] * g1v[i] + b1v[i]));
                *(ushort8*)&PA[ch * 64 + ((o + SWZ(ch)) & 7) * 8] = u;
            }
        }
        __syncthreads();

        #pragma unroll
        for (int kk = 0; kk < 2; ++kk) {
            short8 af[4], bf[8];
            #pragma unroll
            for (int dt = 0; dt < 4; ++dt) {
                int ch = wd * 64 + dt * 16 + l15;
                af[dt] = *(const short8*)&PA[ch * 64 + (((kk << 2) + kgrp + SWZ(ch)) & 7) * 8];
            }
            #pragma unroll
            for (int et = 0; et < 8; ++et) {
                int ch = we * 128 + et * 16 + l15;
                bf[et] = *(const short8*)&PB[ch * 64 + (((kk << 2) + kgrp + SWZ(ch)) & 7) * 8];
            }
            #pragma unroll
            for (int dt = 0; dt < 4; ++dt)
                #pragma unroll
                for (int et = 0; et < 8; ++et)
                    acc[dt][et] = __builtin_amdgcn_mfma_f32_16x16x32_bf16(af[dt], bf[et], acc[dt][et], 0, 0, 0);
        }
    }

    size_t obase = ((size_t)ks_i * Bc + b) * (Dd * Dd);
    #pragma unroll
    for (int dt = 0; dt < 4; ++dt) {
        #pragma unroll
        for (int r = 0; r < 4; ++r) {
            int d = wd * 64 + dt * 16 + kgrp * 4 + r;
            float* rowp = ctxp + obase + (size_t)d * Dd + we * 128 + l15;
            #pragma unroll
            for (int et = 0; et < 8; ++et)
                rowp[et * 16] = acc[dt][et][r];
        }
    }
}

// K5: reduce ctx partials, scale by 1/colsum, bitonic sort (desc), 4 top-k thresholds,
// combined masked softmax M = sum_i a_i * softmax_masked_i.  grid = B*D rows.
__global__ __launch_bounds__(256) void mg_k5_mask(const float* __restrict__ a1p, const float* __restrict__ a2p,
                                                  const float* __restrict__ a3p, const float* __restrict__ a4p,
                                                  float* __restrict__ ws, int nks)
{
    const float* ctxp   = ws + OFF_CTXP;
    const float* colsum = ws + OFF_COLSUM;
    float* Mo = ws + OFF_M;
    int t = threadIdx.x;
    int b = blockIdx.x >> 8, d = blockIdx.x & 255;
    __shared__ float s[256];
    __shared__ float wred[4][4];

    float c = 0.f;
    for (int p = 0; p < nks; ++p)
        c += ctxp[((size_t)p * Bc + b) * (Dd * Dd) + (size_t)d * Dd + t];
    float inv = 1.f / colsum[b * Dd + d];
    c *= inv;
    s[t] = c;
    __syncthreads();
    for (int k = 2; k <= 256; k <<= 1) {
        for (int j = k >> 1; j > 0; j >>= 1) {
            int ixj = t ^ j;
            if (ixj > t) {
                float A = s[t], Bv = s[ixj];
                bool desc = ((t & k) == 0);
                bool sw = desc ? (A < Bv) : (A > Bv);
                if (sw) { s[t] = Bv; s[ixj] = A; }
            }
            __syncthreads();
        }
    }
    float cmax = s[0];
    float t0 = s[127], t1 = s[169], t2 = s[191], t3 = s[203];  // k-1 for k = 128,170,192,204
    float e = __expf(c - cmax);
    float w0 = (c >= t0) ? e : 0.f;
    float w1 = (c >= t1) ? e : 0.f;
    float w2 = (c >= t2) ? e : 0.f;
    float w3 = (c >= t3) ? e : 0.f;
    float v0 = w0, v1 = w1, v2 = w2, v3 = w3;
    #pragma unroll
    for (int m = 1; m < 64; m <<= 1) {
        v0 += __shfl_xor(v0, m); v1 += __shfl_xor(v1, m);
        v2 += __shfl_xor(v2, m); v3 += __shfl_xor(v3, m);
    }
    int lane = t & 63, wv = t >> 6;
    if (lane == 0) { wred[wv][0] = v0; wred[wv][1] = v1; wred[wv][2] = v2; wred[wv][3] = v3; }
    __syncthreads();
    float S0 = wred[0][0] + wred[1][0] + wred[2][0] + wred[3][0];
    float S1 = wred[0][1] + wred[1][1] + wred[2][1] + wred[3][1];
    float S2 = wred[0][2] + wred[1][2] + wred[2][2] + wred[3][2];
    float S3 = wred[0][3] + wred[1][3] + wred[2][3] + wred[3][3];
    float Mv = a1p[0] * (w0 / S0) + a2p[0] * (w1 / S1) + a3p[0] * (w2 / S2) + a4p[0] * (w3 / S3);
    Mo[(b * Dd + d) * Dd + t] = Mv;
}

// K6: W2 bf16 in FRAG-LINEAR layout for K7's LDS staging:
// ushort idx = ((b*8+ks)*16384) + wave*2048 + ot*512 + (kgrp*16+colA)*8 + j
// where o = wave*64+ot*16+colA, e = ks*32+kgrp*8+j.
__global__ __launch_bounds__(256) void mg_k6_w2(const float* __restrict__ Wr, float* __restrict__ ws)
{
    const float* Mo = ws + OFF_M;
    ushort* W2B = (ushort*)(ws + OFF_W2T);
    __shared__ float Mt[32][128];
    __shared__ float WrT[32][36];
    int t = threadIdx.x;
    int b = blockIdx.x >> 5, ob = (blockIdx.x >> 1) & 15, eh = blockIdx.x & 1;
    int o0 = ob * 32, e0 = eh * 128;
    int ol4 = t & 7, el = t >> 3;
    float acc[4][4];
    #pragma unroll
    for (int i = 0; i < 4; ++i)
        #pragma unroll
        for (int j = 0; j < 4; ++j) acc[i][j] = 0.f;

    for (int ch = 0; ch < 8; ++ch) {
        int c0 = ch * 32;
        __syncthreads();
        #pragma unroll
        for (int k = 0; k < 4; ++k) {
            int fi = t + k * 256;
            int row = fi >> 5, c4 = fi & 31;
            float4 mv = ((const float4*)Mo)[(b * Dd + c0 + row) * 64 + (e0 >> 2) + c4];
            *(float4*)&Mt[row][c4 * 4] = mv;
        }
        {
            int ol = t >> 3, c4 = t & 7;
            float4 wv = ((const float4*)Wr)[(o0 + ol) * 64 + (c0 >> 2) + c4];
            WrT[c4 * 4 + 0][ol] = wv.x;
            WrT[c4 * 4 + 1][ol] = wv.y;
            WrT[c4 * 4 + 2][ol] = wv.z;
            WrT[c4 * 4 + 3][ol] = wv.w;
        }
        __syncthreads();
        #pragma unroll
        for (int cc = 0; cc < 32; ++cc) {
            float4 w4 = *(const float4*)&WrT[cc][ol4 * 4];
            float4 m4 = *(const float4*)&Mt[cc][el * 4];
            float wv[4] = {w4.x, w4.y, w4.z, w4.w};
            float mv[4] = {m4.x, m4.y, m4.z, m4.w};
            #pragma unroll
            for (int i = 0; i < 4; ++i)
                #pragma unroll
                for (int j = 0; j < 4; ++j)
                    acc[i][j] = fmaf(wv[i], mv[j], acc[i][j]);
        }
    }
    {
        int e_base = e0 + el * 4;
        int ks = e_base >> 5;
        int kg = (e_base >> 3) & 3, jj = e_base & 7;   // jj in {0,4}
        #pragma unroll
        for (int i = 0; i < 4; ++i) {
            int o = o0 + ol4 * 4 + i;
            int wv2 = o >> 6, ot = (o >> 4) & 3, cA = o & 15;
            ushort4 u;
            u.x = f2bf(acc[i][0]); u.y = f2bf(acc[i][1]);
            u.z = f2bf(acc[i][2]); u.w = f2bf(acc[i][3]);
            size_t idx = ((size_t)b * 8 + ks) * 16384 + wv2 * 2048 + ot * 512
                       + (kg * 16 + cA) * 8 + jj;
            *(ushort4*)&W2B[idx] = u;
        }
    }
}

// K7 v10 (wave-private W2 staging, NO per-K-step barrier): each wave stages and reads
// only its own wave*2048 slice of W0/W1, so block-wide sync is unnecessary inside the
// K-loop -- a wave-local s_waitcnt vmcnt(0) suffices. Waves drift freely, hiding each
// other's stage latency. Barriers remain only for qsT (start) and stat overlay (end).
__global__ __launch_bounds__(512) void mg_k7_final(const float* __restrict__ x2,
        const float* __restrict__ g1, const float* __restrict__ b1,
        const float* __restrict__ br, const float* __restrict__ g2, const float* __restrict__ b2,
        const float* __restrict__ ws, float* __restrict__ out)
{
    __shared__ ushort smem[8192 + 2 * 16384];   // qsT 16KB + W2 dbuf 64KB = 80KB
    ushort* qsT = smem;
    ushort* W0 = smem + 8192;
    ushort* W1 = smem + 8192 + 16384;

    const float* mu2    = ws + OFF_MU2;
    const float* rstd2  = ws + OFF_RSTD2;
    const float* rowinv = ws + OFF_ROWINV;
    const ushort* W2B   = (const ushort*)(ws + OFF_W2T);

    int t = threadIdx.x;
    int b = blockIdx.x / 288, nt0 = blockIdx.x % 288;
    int n0 = nt0 * 32;
    int lw = t & 63, wave = t >> 6;
    int colA = lw & 15, kgrp = lw >> 4;

#define STAGEW(dstbuf, ksv)                                                        \
    {                                                                              \
        size_t so_ = ((size_t)b * 8 + (ksv)) * 16384 + wave * 2048;                \
        _Pragma("unroll")                                                          \
        for (int k_ = 0; k_ < 4; ++k_) {                                           \
            __builtin_amdgcn_global_load_lds(                                      \
                (const __attribute__((address_space(1))) unsigned int*)            \
                    (W2B + so_ + k_ * 512 + lw * 8),                               \
                (__attribute__((address_space(3))) unsigned int*)                  \
                    ((dstbuf) + wave * 2048 + k_ * 512),                           \
                16, 0, 0);                                                         \
        }                                                                          \
    }

    STAGEW(W0, 0);

    {
        int row = t >> 4, gpair = (t & 15) * 2;
        int ni = b * Nn + n0 + row;
        float m = mu2[ni], r = rstd2[ni], ri = rowinv[ni];
        #pragma unroll
        for (int jj = 0; jj < 2; ++jj) {
            int g = gpair + jj;
            const float4* xp = (const float4*)x2 + (size_t)ni * 64 + g * 2;
            float4 xa = xp[0], xb = xp[1];
            float4 ga = ((const float4*)g1)[g * 2], gc = ((const float4*)g1)[g * 2 + 1];
            float4 ba = ((const float4*)b1)[g * 2], bc = ((const float4*)b1)[g * 2 + 1];
            float v[8]  = {xa.x, xa.y, xa.z, xa.w, xb.x, xb.y, xb.z, xb.w};
            float gv[8] = {ga.x, ga.y, ga.z, ga.w, gc.x, gc.y, gc.z, gc.w};
            float bv[8] = {ba.x, ba.y, ba.z, ba.w, bc.x, bc.y, bc.z, bc.w};
            ushort8 u;
            #pragma unroll
            for (int q = 0; q < 8; ++q)
                u[q] = f2bf(__expf((v[q] - m) * r * gv[q] + bv[q]) * ri);
            *(ushort8*)&qsT[row * 256 + ((g ^ (row & 7)) << 3)] = u;
        }
    }
    __syncthreads();   // qsT visible to all waves; W0 (wave-private) also drained

    f32x4 acc[4][2];
    #pragma unroll
    for (int ot = 0; ot < 4; ++ot) {
        acc[ot][0] = (f32x4){0.f, 0.f, 0.f, 0.f};
        acc[ot][1] = (f32x4){0.f, 0.f, 0.f, 0.f};
    }

    #pragma unroll
    for (int ks = 0; ks < 8; ++ks) {
        if (ks < 7) {
            if ((ks & 1) == 0) { STAGEW(W1, ks + 1); }
            else               { STAGEW(W0, ks + 1); }
        }
        const ushort* wb = (ks & 1) ? W1 : W0;
        int gsl = ((ks * 4 + kgrp) ^ (colA & 7)) << 3;
        short8 bf0 = *(const short8*)&qsT[colA * 256 + gsl];
        short8 bf1 = *(const short8*)&qsT[(16 + colA) * 256 + gsl];
        #pragma unroll
        for (int ot = 0; ot < 4; ++ot) {
            short8 af = *(const short8*)&wb[wave * 2048 + ot * 512 + lw * 8];
            acc[ot][0] = __builtin_amdgcn_mfma_f32_16x16x32_bf16(af, bf0, acc[ot][0], 0, 0, 0);
            acc[ot][1] = __builtin_amdgcn_mfma_f32_16x16x32_bf16(af, bf1, acc[ot][1], 0, 0, 0);
        }
        if (ks < 7) {
            // wave-local drain of this wave's global_load_lds into the other buffer;
            // no block barrier needed (buffers are wave-private slices).
            asm volatile("s_waitcnt vmcnt(0)" ::: "memory");
            __builtin_amdgcn_sched_barrier(0);
        }
    }
#undef STAGEW

    __syncthreads();   // all waves done reading qsT before stat overlay

    float (*stat)[2][16][2] = (float (*)[2][16][2])(void*)smem;
    float (*musig)[2] = (float (*)[2])((float*)(void*)smem + 512);

    float ps[2] = {0.f, 0.f}, pq[2] = {0.f, 0.f};
    #pragma unroll
    for (int ot = 0; ot < 4; ++ot) {
        #pragma unroll
        for (int r = 0; r < 4; ++r) {
            int o = wave * 64 + ot * 16 + kgrp * 4 + r;
            float bb = br[o];
            float v0 = acc[ot][0][r] + bb;
            float v1 = acc[ot][1][r] + bb;
            acc[ot][0][r] = v0; acc[ot][1][r] = v1;
            ps[0] += v0; pq[0] += v0 * v0;
            ps[1] += v1; pq[1] += v1 * v1;
        }
    }
    #pragma unroll
    for (int m = 16; m <= 32; m <<= 1) {
        ps[0] += __shfl_xor(ps[0], m); pq[0] += __shfl_xor(pq[0], m);
        ps[1] += __shfl_xor(ps[1], m); pq[1] += __shfl_xor(pq[1], m);
    }
    if (lw < 16) {
        stat[wave][0][lw][0] = ps[0]; stat[wave][0][lw][1] = pq[0];
        stat[wave][1][lw][0] = ps[1]; stat[wave][1][lw][1] = pq[1];
    }
    __syncthreads();
    if (t < 32) {
        int ntl = t >> 4, col = t & 15;
        float S = 0.f, Q = 0.f;
        #pragma unroll
        for (int w2 = 0; w2 < 8; ++w2) { S += stat[w2][ntl][col][0]; Q += stat[w2][ntl][col][1]; }
        float mu = S * (1.f / Oo);
        float var = Q * (1.f / Oo) - mu * mu;
        musig[t][0] = mu;
        musig[t][1] = rsqrtf(var + EPSc);
    }
    __syncthreads();

    float mn0 = musig[colA][0],      rs0 = musig[colA][1];
    float mn1 = musig[16 + colA][0], rs1 = musig[16 + colA][1];
    #pragma unroll
    for (int ot = 0; ot < 4; ++ot) {
        #pragma unroll
        for (int r = 0; r < 4; ++r) {
            int o = wave * 64 + ot * 16 + kgrp * 4 + r;
            float gg = g2[o], bb2 = b2[o];
            size_t ob = ((size_t)b * Oo + o) * Nn + n0;
            out[ob + colA]      = (acc[ot][0][r] - mn0) * rs0 * gg + bb2;
            out[ob + 16 + colA] = (acc[ot][1][r] - mn1) * rs1 * gg + bb2;
        }
    }
}

extern "C" void kernel_launch(void* const* d_in, const int* in_sizes, int n_in,
                              void* d_out, int out_size, void* d_ws, size_t ws_size,
                              hipStream_t stream)
{
    (void)in_sizes; (void)n_in; (void)out_size;
    const float* x1 = (const float*)d_in[0];
    const float* x2 = (const float*)d_in[1];
    const float* g1 = (const float*)d_in[2];
    const float* b1 = (const float*)d_in[3];
    const float* Wr = (const float*)d_in[4];
    const float* br = (const float*)d_in[5];
    const float* g2 = (const float*)d_in[6];
    const float* b2 = (const float*)d_in[7];
    const float* a1 = (const float*)d_in[8];
    const float* a2 = (const float*)d_in[9];
    const float* a3 = (const float*)d_in[10];
    const float* a4 = (const float*)d_in[11];
    float* ws = (float*)d_ws;
    float* out = (float*)d_out;

    // adaptive split-K: nks must divide 144 (so krange % 64 == 0) and partials must fit ws
    const int cand[6] = {24, 16, 12, 8, 4, 2};
    int nks = 2;
    for (int ci = 0; ci < 6; ++ci) {
        if (((size_t)OFF_CTXP + (size_t)cand[ci] * 524288ull) * 4ull <= ws_size) { nks = cand[ci]; break; }
    }

    hipLaunchKernelGGL(mg_k0_zero, dim3(2), dim3(256), 0, stream, ws + OFF_COLSUM, 512);
    hipLaunchKernelGGL(mg_k1_stats, dim3(1152), dim3(256), 0, stream, x1, x2, g1, b1, ws);
    hipLaunchKernelGGL(mg_k3_ctx, dim3(Bc * nks), dim3(512), 0, stream, x1, x2, g1, b1, ws, nks);
    hipLaunchKernelGGL(mg_k5_mask, dim3(2048), dim3(256), 0, stream, a1, a2, a3, a4, ws, nks);
    hipLaunchKernelGGL(mg_k6_w2, dim3(256), dim3(256), 0, stream, Wr, ws);
    hipLaunchKernelGGL(mg_k7_final, dim3(2304), dim3(512), 0, stream, x2, g1, b1, br, g2, b2, ws, out);
}